// Round 7
// baseline (668.468 us; speedup 1.0000x reference)
//
#include <hip/hip_runtime.h>
#include <math.h>

typedef __bf16 bf16;
typedef __attribute__((ext_vector_type(8))) __bf16 bf16x8;
typedef __attribute__((ext_vector_type(4))) float f32x4;

#define NBLK 128      // edge-partition blocks for binning (128 optimal: r13's 512 regressed)
#define NB_MAX 1600   // max buckets (N/64); N=100000 -> 1563

__device__ __forceinline__ void bn_coeffs(const float* st, const float* g,
                                          const float* be, float inv_n, int d,
                                          float& sc, float& sh) {
  float mean = st[d] * inv_n;
  float var = st[64 + d] * inv_n - mean * mean;
  sc = g[d] * rsqrtf(var + 1e-5f);
  sh = be[d] - mean * sc;
}

// ---------------- edge binning (bucket = dst>>6) ----------------
__global__ __launch_bounds__(256) void bin_hist_kernel(const int* __restrict__ dst,
                                                       int* __restrict__ cnt,
                                                       int E, int ch, int nb) {
  __shared__ int lcnt[NB_MAX];
  int tid = threadIdx.x, blk = blockIdx.x;
  for (int t = tid; t < nb; t += 256) lcnt[t] = 0;
  __syncthreads();
  int base = blk * ch, eend = min(E, base + ch);
  for (int e = base + tid; e < eend; e += 256) atomicAdd(&lcnt[dst[e] >> 6], 1);
  __syncthreads();
  for (int t = tid; t < nb; t += 256) cnt[blk * nb + t] = lcnt[t];
}

__global__ __launch_bounds__(256) void bin_tot_kernel(const int* __restrict__ cnt,
                                                      int* __restrict__ tot, int nb) {
  int b = blockIdx.x * 256 + threadIdx.x;
  if (b >= nb) return;
  int s = 0;
  for (int blk = 0; blk < NBLK; ++blk) s += cnt[blk * nb + b];
  tot[b] = s;
}

__global__ __launch_bounds__(256) void scan_buckets_kernel(const int* __restrict__ tot,
                                                           int* __restrict__ bucketptr, int nb) {
  __shared__ int lds[256];
  int tid = threadIdx.x;
  const int CH = 7;
  int vals[CH];
  int s = 0;
#pragma unroll
  for (int k = 0; k < CH; ++k) {
    int i = tid * CH + k;
    vals[k] = (i < nb) ? tot[i] : 0;
    s += vals[k];
  }
  lds[tid] = s;
  __syncthreads();
  for (int off = 1; off < 256; off <<= 1) {
    int v = (tid >= off) ? lds[tid - off] : 0;
    __syncthreads();
    lds[tid] += v;
    __syncthreads();
  }
  int run = lds[tid] - s;
  if (tid == 0) bucketptr[0] = 0;
#pragma unroll
  for (int k = 0; k < CH; ++k) {
    int i = tid * CH + k;
    run += vals[k];
    if (i < nb) bucketptr[i + 1] = run;
  }
}

__global__ __launch_bounds__(256) void bin_off_kernel(const int* __restrict__ cnt,
                                                      const int* __restrict__ bucketptr,
                                                      int* __restrict__ woff, int nb) {
  int b = blockIdx.x * 256 + threadIdx.x;
  if (b >= nb) return;
  int run = bucketptr[b];
  for (int blk = 0; blk < NBLK; ++blk) {
    woff[blk * nb + b] = run;
    run += cnt[blk * nb + b];
  }
}

__global__ __launch_bounds__(256) void bin_scatter_kernel(const int* __restrict__ src,
                                                          const int* __restrict__ dst,
                                                          const int* __restrict__ woff,
                                                          int* __restrict__ packed,
                                                          int E, int ch, int nb) {
  __shared__ int cur[NB_MAX];
  int tid = threadIdx.x, blk = blockIdx.x;
  for (int t = tid; t < nb; t += 256) cur[t] = woff[blk * nb + t];
  __syncthreads();
  int base = blk * ch, eend = min(E, base + ch);
  for (int e = base + tid; e < eend; e += 256) {
    int d = dst[e], s = src[e];
    int pos = atomicAdd(&cur[d >> 6], 1);
    packed[pos] = ((d & 63) << 17) | s;
  }
}

// CSR finalize (r1-verified): within each 64-node bucket, group edges by
// (dstLow, src-tile). colidx per node = [tile0|tile1|tile2|tile3] contiguous;
// splits[node*4+k] = start of tile-k segment; node end = rowptr[node+1].
__global__ __launch_bounds__(256) void csr_finalize_kernel(
    const int* __restrict__ packed, const int* __restrict__ bucketptr,
    int* __restrict__ rowptr, int* __restrict__ colidx, int* __restrict__ splits,
    int n, int E, int TN) {
  __shared__ int hist[256], offs[256];
  int tid = threadIdx.x, b = blockIdx.x;
  hist[tid] = 0;
  __syncthreads();
  int beg = bucketptr[b], end = bucketptr[b + 1];
  for (int e = beg + tid; e < end; e += 256) {
    int w = packed[e];
    int s = w & 0x1FFFF;
    int tile = (s >= TN) + (s >= 2 * TN) + (s >= 3 * TN);
    atomicAdd(&hist[((w >> 17) << 2) + tile], 1);
  }
  __syncthreads();
  if (tid == 0) {
    int run = 0;
    for (int j = 0; j < 256; ++j) { offs[j] = run; run += hist[j]; }
  }
  __syncthreads();
  {
    int node = b * 64 + (tid >> 2);
    if (node < n) splits[(size_t)node * 4 + (tid & 3)] = beg + offs[tid];
  }
  if (tid < 64) {
    int idx = b * 64 + tid;
    if (idx < n) rowptr[idx] = beg + offs[tid << 2];
  }
  if (b == 0 && tid == 64) rowptr[n] = E;
  __syncthreads();
  hist[tid] = offs[tid];  // reuse as running cursors
  __syncthreads();
  for (int e = beg + tid; e < end; e += 256) {
    int w = packed[e];
    int s = w & 0x1FFFF;
    int tile = (s >= TN) + (s >= 2 * TN) + (s >= 3 * TN);
    int pos = atomicAdd(&hist[((w >> 17) << 2) + tile], 1);
    colidx[beg + pos] = s;
  }
}

// ------- MFMA GEMM 0 with fused embedding (no x0 materialization) -------
__global__ __launch_bounds__(256) void mfma_gemm0(
    const int* __restrict__ deg, const int* __restrict__ lab,
    const float* __restrict__ ed, const float* __restrict__ el,
    const float* __restrict__ W, bf16* __restrict__ y, int n) {
  __shared__ bf16 As[64][136];
  __shared__ bf16 Bs[64][136];
  int tid = threadIdx.x;
  int nbase = blockIdx.x * 64;
  {
    int r = tid >> 2, c = tid & 3;
    int node = nbase + r;
    union { bf16 hh[32]; uint4 u[4]; } t;
    if (node < n) {
      int idx = (c < 2) ? deg[node] : lab[node];
      const float* srcp = (c < 2) ? (ed + (size_t)idx * 64 + c * 32)
                                  : (el + (size_t)idx * 64 + (c - 2) * 32);
#pragma unroll
      for (int j = 0; j < 8; ++j) {
        float4 f = ((const float4*)srcp)[j];
        t.hh[j * 4 + 0] = (bf16)f.x; t.hh[j * 4 + 1] = (bf16)f.y;
        t.hh[j * 4 + 2] = (bf16)f.z; t.hh[j * 4 + 3] = (bf16)f.w;
      }
    } else {
#pragma unroll
      for (int j = 0; j < 4; ++j) t.u[j] = uint4{0, 0, 0, 0};
    }
#pragma unroll
    for (int j = 0; j < 4; ++j) *(uint4*)&As[r][c * 32 + j * 8] = t.u[j];
    const float4* wp = (const float4*)(W + r * 128 + c * 32);
#pragma unroll
    for (int j = 0; j < 4; ++j) {
      float4 f0 = wp[j * 2], f1 = wp[j * 2 + 1];
      union { bf16 h[8]; uint4 u; } tw;
      tw.h[0] = (bf16)f0.x; tw.h[1] = (bf16)f0.y; tw.h[2] = (bf16)f0.z; tw.h[3] = (bf16)f0.w;
      tw.h[4] = (bf16)f1.x; tw.h[5] = (bf16)f1.y; tw.h[6] = (bf16)f1.z; tw.h[7] = (bf16)f1.w;
      *(uint4*)&Bs[r][c * 32 + j * 8] = tw.u;
    }
  }
  __syncthreads();
  int l = tid & 63, w = tid >> 6, m = l & 15, quad = l >> 4;
  f32x4 acc[4] = {{0.f, 0.f, 0.f, 0.f}, {0.f, 0.f, 0.f, 0.f},
                  {0.f, 0.f, 0.f, 0.f}, {0.f, 0.f, 0.f, 0.f}};
#pragma unroll
  for (int k0 = 0; k0 < 128; k0 += 32) {
    bf16x8 a = *(const bf16x8*)&As[w * 16 + m][k0 + quad * 8];
#pragma unroll
    for (int t = 0; t < 4; ++t) {
      bf16x8 b = *(const bf16x8*)&Bs[t * 16 + m][k0 + quad * 8];
      acc[t] = __builtin_amdgcn_mfma_f32_16x16x32_bf16(a, b, acc[t], 0, 0, 0);
    }
  }
#pragma unroll
  for (int t = 0; t < 4; ++t)
#pragma unroll
    for (int r4 = 0; r4 < 4; ++r4) {
      int node = nbase + w * 16 + quad * 4 + r4;
      if (node < n) y[(size_t)node * 64 + t * 16 + m] = (bf16)acc[t][r4];
    }
}

// ------- MFMA GEMM (layers 1,2) -------
__global__ __launch_bounds__(256) void mfma_gemm_bn(
    const bf16* __restrict__ hin, const float* __restrict__ st,
    const float* __restrict__ g, const float* __restrict__ be, float inv_n,
    const float* __restrict__ W, bf16* __restrict__ z,
    bf16* __restrict__ y, int n) {
  __shared__ bf16 As[64][72];
  __shared__ bf16 Bs[64][72];
  __shared__ float ssc[64], ssh[64];
  int tid = threadIdx.x;
  int nbase = blockIdx.x * 64;
  if (tid < 64) {
    float sc, sh;
    bn_coeffs(st, g, be, inv_n, tid, sc, sh);
    ssc[tid] = sc; ssh[tid] = sh;
  }
  __syncthreads();
  {
    int r = tid >> 2, c = tid & 3;
    int node = nbase + r;
    union { bf16 h[16]; uint4 u[2]; } t;
    if (node < n) {
      const uint4* p = (const uint4*)(hin + (size_t)node * 64 + c * 16);
      union { uint4 u; bf16 h[8]; } a0, a1;
      a0.u = p[0]; a1.u = p[1];
#pragma unroll
      for (int j = 0; j < 8; ++j) {
        int d = c * 16 + j;
        float v = (float)a0.h[j] * ssc[d] + ssh[d];
        v = (v >= 0.f) ? v : 0.01f * v;
        t.h[j] = (bf16)v;
      }
#pragma unroll
      for (int j = 0; j < 8; ++j) {
        int d = c * 16 + 8 + j;
        float v = (float)a1.h[j] * ssc[d] + ssh[d];
        v = (v >= 0.f) ? v : 0.01f * v;
        t.h[8 + j] = (bf16)v;
      }
      *(uint4*)(z + (size_t)node * 64 + c * 16) = t.u[0];
      *(uint4*)(z + (size_t)node * 64 + c * 16 + 8) = t.u[1];
    } else {
      t.u[0] = uint4{0, 0, 0, 0}; t.u[1] = uint4{0, 0, 0, 0};
    }
    *(uint4*)&As[r][c * 16] = t.u[0];
    *(uint4*)&As[r][c * 16 + 8] = t.u[1];
    const float4* wp = (const float4*)(W + r * 64 + c * 16);
#pragma unroll
    for (int j = 0; j < 2; ++j) {
      float4 f0 = wp[j * 2], f1 = wp[j * 2 + 1];
      union { bf16 h[8]; uint4 u; } tw;
      tw.h[0] = (bf16)f0.x; tw.h[1] = (bf16)f0.y; tw.h[2] = (bf16)f0.z; tw.h[3] = (bf16)f0.w;
      tw.h[4] = (bf16)f1.x; tw.h[5] = (bf16)f1.y; tw.h[6] = (bf16)f1.z; tw.h[7] = (bf16)f1.w;
      *(uint4*)&Bs[r][c * 16 + j * 8] = tw.u;
    }
  }
  __syncthreads();
  int l = tid & 63, w = tid >> 6, m = l & 15, quad = l >> 4;
  f32x4 acc[4] = {{0.f, 0.f, 0.f, 0.f}, {0.f, 0.f, 0.f, 0.f},
                  {0.f, 0.f, 0.f, 0.f}, {0.f, 0.f, 0.f, 0.f}};
#pragma unroll
  for (int k0 = 0; k0 < 64; k0 += 32) {
    bf16x8 a = *(const bf16x8*)&As[w * 16 + m][k0 + quad * 8];
#pragma unroll
    for (int t = 0; t < 4; ++t) {
      bf16x8 b = *(const bf16x8*)&Bs[t * 16 + m][k0 + quad * 8];
      acc[t] = __builtin_amdgcn_mfma_f32_16x16x32_bf16(a, b, acc[t], 0, 0, 0);
    }
  }
#pragma unroll
  for (int t = 0; t < 4; ++t)
#pragma unroll
    for (int r4 = 0; r4 < 4; ++r4) {
      int node = nbase + w * 16 + quad * 4 + r4;
      if (node < n) y[(size_t)node * 64 + t * 16 + m] = (bf16)acc[t][r4];
    }
}

// ------- gather v7: v5 load engine + src-tile phases, register accumulators -------
// Block = one 64-node bucket (grid = NB = 1563, fully co-resident -> the 4 tile
// phases stay soft-aligned across the grid with NO barrier; per-bucket work is
// balanced +-3%). Each 16-lane group owns 4 nodes with acc[4][4] f32 persisting
// in registers across phases; lane lh holds dims [4lh,4lh+4) as uint2. Per phase
// k, only src-tile k (~3.2MB of y <= 4MB XCD L2) is read by the whole grid ->
// the ~16x per-row reuse hits the XCD-local L2 instead of the L3/fabric path.
// Dual-node interleave, 4-edge predicated straight-line trips: 8 y-load instrs
// in flight (32 lines/wave, v5's proven MLP); colidx->y is the only dep chain.
__global__ __launch_bounds__(256, 4) void gather_kernel(
    const bf16* __restrict__ y, const int* __restrict__ rowptr,
    const int* __restrict__ splits, const int* __restrict__ colidx,
    const float* __restrict__ bias, bf16* __restrict__ h,
    float* __restrict__ stats, int n) {
  __shared__ float s_sum[64], s_sq[64];
  int tid = threadIdx.x;
  if (tid < 64) { s_sum[tid] = 0.f; s_sq[tid] = 0.f; }
  __syncthreads();
  int lane = tid & 63, wv = tid >> 6;
  int g = lane >> 4, lh = lane & 15;
  int base = (blockIdx.x << 6) + (wv << 4) + (g << 2);  // first of this group's 4 nodes
  const uint2* y2 = (const uint2*)y;
  uint2* h2 = (uint2*)h;
  float b0 = bias[4 * lh + 0], b1 = bias[4 * lh + 1];
  float b2 = bias[4 * lh + 2], b3 = bias[4 * lh + 3];
  float acc[4][4];
#pragma unroll
  for (int j = 0; j < 4; ++j)
#pragma unroll
    for (int d = 0; d < 4; ++d) acc[j][d] = 0.f;

#define ACCJ(j, d)                                                   \
  {                                                                  \
    union { unsigned u; float f; } t_;                               \
    t_.u = (d).x << 16;         acc[j][0] += t_.f;                   \
    t_.u = (d).x & 0xFFFF0000u; acc[j][1] += t_.f;                   \
    t_.u = (d).y << 16;         acc[j][2] += t_.f;                   \
    t_.u = (d).y & 0xFFFF0000u; acc[j][3] += t_.f;                   \
  }

#pragma unroll 1
  for (int k = 0; k < 4; ++k) {
#pragma unroll
    for (int jp = 0; jp < 4; jp += 2) {
      int nA = base + jp, nB = base + jp + 1;
      bool vA = nA < n, vB = nB < n;
      int eA = 0, fA = 0, eB = 0, fB = 0;
      if (vA) {
        eA = splits[(size_t)nA * 4 + k];
        fA = (k == 3) ? rowptr[nA + 1] : splits[(size_t)nA * 4 + k + 1];
      }
      if (vB) {
        eB = splits[(size_t)nB * 4 + k];
        fB = (k == 3) ? rowptr[nB + 1] : splits[(size_t)nB * 4 + k + 1];
      }
      while (__ballot(eA < fA || eB < fB) != 0ull) {
        uint2 dA0 = {0u, 0u}, dA1 = {0u, 0u}, dA2 = {0u, 0u}, dA3 = {0u, 0u};
        uint2 dB0 = {0u, 0u}, dB1 = {0u, 0u}, dB2 = {0u, 0u}, dB3 = {0u, 0u};
        if (eA + 0 < fA) { int s = colidx[eA + 0]; dA0 = y2[(size_t)s * 16 + lh]; }
        if (eA + 1 < fA) { int s = colidx[eA + 1]; dA1 = y2[(size_t)s * 16 + lh]; }
        if (eA + 2 < fA) { int s = colidx[eA + 2]; dA2 = y2[(size_t)s * 16 + lh]; }
        if (eA + 3 < fA) { int s = colidx[eA + 3]; dA3 = y2[(size_t)s * 16 + lh]; }
        if (eB + 0 < fB) { int s = colidx[eB + 0]; dB0 = y2[(size_t)s * 16 + lh]; }
        if (eB + 1 < fB) { int s = colidx[eB + 1]; dB1 = y2[(size_t)s * 16 + lh]; }
        if (eB + 2 < fB) { int s = colidx[eB + 2]; dB2 = y2[(size_t)s * 16 + lh]; }
        if (eB + 3 < fB) { int s = colidx[eB + 3]; dB3 = y2[(size_t)s * 16 + lh]; }
        ACCJ(jp, dA0); ACCJ(jp, dA1); ACCJ(jp, dA2); ACCJ(jp, dA3);
        ACCJ(jp + 1, dB0); ACCJ(jp + 1, dB1); ACCJ(jp + 1, dB2); ACCJ(jp + 1, dB3);
        eA = min(eA + 4, fA);
        eB = min(eB + 4, fB);
      }
    }
  }
#undef ACCJ

  float p0 = 0.f, p1 = 0.f, p2 = 0.f, p3 = 0.f;
  float q0 = 0.f, q1 = 0.f, q2 = 0.f, q3 = 0.f;
#pragma unroll
  for (int j = 0; j < 4; ++j) {
    int node = base + j;
    if (node < n) {
      uint2 sd = y2[(size_t)node * 16 + lh];
      float s0, s1, s2, s3;
      {
        union { unsigned u; float f; } t_;
        t_.u = sd.x << 16;         s0 = t_.f;
        t_.u = sd.x & 0xFFFF0000u; s1 = t_.f;
        t_.u = sd.y << 16;         s2 = t_.f;
        t_.u = sd.y & 0xFFFF0000u; s3 = t_.f;
      }
      float v0 = acc[j][0] + s0 + b0;
      float v1 = acc[j][1] + s1 + b1;
      float v2 = acc[j][2] + s2 + b2;
      float v3 = acc[j][3] + s3 + b3;
      union { bf16 hh[4]; uint2 u; } o;
      o.hh[0] = (bf16)v0; o.hh[1] = (bf16)v1;
      o.hh[2] = (bf16)v2; o.hh[3] = (bf16)v3;
      h2[(size_t)node * 16 + lh] = o.u;
      p0 += v0; q0 += v0 * v0;
      p1 += v1; q1 += v1 * v1;
      p2 += v2; q2 += v2 * v2;
      p3 += v3; q3 += v3 * v3;
    }
  }
  atomicAdd(&s_sum[4 * lh + 0], p0); atomicAdd(&s_sq[4 * lh + 0], q0);
  atomicAdd(&s_sum[4 * lh + 1], p1); atomicAdd(&s_sq[4 * lh + 1], q1);
  atomicAdd(&s_sum[4 * lh + 2], p2); atomicAdd(&s_sq[4 * lh + 2], q2);
  atomicAdd(&s_sum[4 * lh + 3], p3); atomicAdd(&s_sq[4 * lh + 3], q3);
  __syncthreads();
  if (tid < 64) {
    atomicAdd(&stats[tid], s_sum[tid]);
    atomicAdd(&stats[64 + tid], s_sq[tid]);
  }
}

// ------- final MLP over concat [emb(deg,lab)|z1|z2|bnleaky(h2)] (320 -> 64), MFMA -------
__global__ __launch_bounds__(256) void mfma_final(
    const int* __restrict__ deg, const int* __restrict__ lab,
    const float* __restrict__ ed, const float* __restrict__ el,
    const bf16* __restrict__ z1, const bf16* __restrict__ z2,
    const bf16* __restrict__ h2, const float* __restrict__ st2,
    const float* __restrict__ g2, const float* __restrict__ be2, float inv_n,
    const float* __restrict__ fw1, const float* __restrict__ fb1,
    bf16* __restrict__ hf, float* __restrict__ stats, int n) {
  __shared__ bf16 As[64][136];
  __shared__ bf16 Bs[64][136];
  __shared__ float s_sum[64], s_sq[64], ssc[64], ssh[64];
  int tid = threadIdx.x;
  if (tid < 64) {
    s_sum[tid] = 0.f; s_sq[tid] = 0.f;
    float sc, sh;
    bn_coeffs(st2, g2, be2, inv_n, tid, sc, sh);
    ssc[tid] = sc; ssh[tid] = sh;
  }
  int nbase = blockIdx.x * 64;
  int l = tid & 63, w = tid >> 6, m = l & 15, quad = l >> 4;
  int r = tid >> 2, c = tid & 3;
  int node_r = nbase + r;
  f32x4 acc[4] = {{0.f, 0.f, 0.f, 0.f}, {0.f, 0.f, 0.f, 0.f},
                  {0.f, 0.f, 0.f, 0.f}, {0.f, 0.f, 0.f, 0.f}};

#pragma unroll
  for (int seg = 0; seg < 4; ++seg) {
    __syncthreads();
    if (seg == 0) {
      union { bf16 hh[32]; uint4 u[4]; } t;
      if (node_r < n) {
        int idx = (c < 2) ? deg[node_r] : lab[node_r];
        const float* srcp = (c < 2) ? (ed + (size_t)idx * 64 + c * 32)
                                    : (el + (size_t)idx * 64 + (c - 2) * 32);
#pragma unroll
        for (int j = 0; j < 8; ++j) {
          float4 f = ((const float4*)srcp)[j];
          t.hh[j * 4 + 0] = (bf16)f.x; t.hh[j * 4 + 1] = (bf16)f.y;
          t.hh[j * 4 + 2] = (bf16)f.z; t.hh[j * 4 + 3] = (bf16)f.w;
        }
      } else {
#pragma unroll
        for (int j = 0; j < 4; ++j) t.u[j] = uint4{0, 0, 0, 0};
      }
#pragma unroll
      for (int j = 0; j < 4; ++j) *(uint4*)&As[r][c * 32 + j * 8] = t.u[j];
      const float4* wp = (const float4*)(fw1 + r * 320 + c * 32);
#pragma unroll
      for (int j = 0; j < 4; ++j) {
        float4 f0 = wp[j * 2], f1 = wp[j * 2 + 1];
        union { bf16 h[8]; uint4 u; } tw;
        tw.h[0] = (bf16)f0.x; tw.h[1] = (bf16)f0.y; tw.h[2] = (bf16)f0.z; tw.h[3] = (bf16)f0.w;
        tw.h[4] = (bf16)f1.x; tw.h[5] = (bf16)f1.y; tw.h[6] = (bf16)f1.z; tw.h[7] = (bf16)f1.w;
        *(uint4*)&Bs[r][c * 32 + j * 8] = tw.u;
      }
    } else if (seg < 3) {
      const bf16* zz = (seg == 1) ? z1 : z2;
      uint4 v[2] = {};
      if (node_r < n) {
        const uint4* p = (const uint4*)(zz + (size_t)node_r * 64 + c * 16);
        v[0] = p[0]; v[1] = p[1];
      }
      *(uint4*)&As[r][c * 16] = v[0];
      *(uint4*)&As[r][c * 16 + 8] = v[1];
      const float4* wp = (const float4*)(fw1 + r * 320 + (seg == 1 ? 128 : 192) + c * 16);
#pragma unroll
      for (int j = 0; j < 2; ++j) {
        float4 f0 = wp[j * 2], f1 = wp[j * 2 + 1];
        union { bf16 h[8]; uint4 u; } t;
        t.h[0] = (bf16)f0.x; t.h[1] = (bf16)f0.y; t.h[2] = (bf16)f0.z; t.h[3] = (bf16)f0.w;
        t.h[4] = (bf16)f1.x; t.h[5] = (bf16)f1.y; t.h[6] = (bf16)f1.z; t.h[7] = (bf16)f1.w;
        *(uint4*)&Bs[r][c * 16 + j * 8] = t.u;
      }
    } else {
      union { bf16 h[16]; uint4 u[2]; } t;
      if (node_r < n) {
        const uint4* p = (const uint4*)(h2 + (size_t)node_r * 64 + c * 16);
        union { uint4 u; bf16 h[8]; } a0, a1;
        a0.u = p[0]; a1.u = p[1];
#pragma unroll
        for (int j = 0; j < 8; ++j) {
          int d = c * 16 + j;
          float v = (float)a0.h[j] * ssc[d] + ssh[d];
          v = (v >= 0.f) ? v : 0.01f * v;
          t.h[j] = (bf16)v;
        }
#pragma unroll
        for (int j = 0; j < 8; ++j) {
          int d = c * 16 + 8 + j;
          float v = (float)a1.h[j] * ssc[d] + ssh[d];
          v = (v >= 0.f) ? v : 0.01f * v;
          t.h[8 + j] = (bf16)v;
        }
      } else {
        t.u[0] = uint4{0, 0, 0, 0}; t.u[1] = uint4{0, 0, 0, 0};
      }
      *(uint4*)&As[r][c * 16] = t.u[0];
      *(uint4*)&As[r][c * 16 + 8] = t.u[1];
      const float4* wp = (const float4*)(fw1 + r * 320 + 256 + c * 16);
#pragma unroll
      for (int j = 0; j < 2; ++j) {
        float4 f0 = wp[j * 2], f1 = wp[j * 2 + 1];
        union { bf16 h[8]; uint4 u; } tw;
        tw.h[0] = (bf16)f0.x; tw.h[1] = (bf16)f0.y; tw.h[2] = (bf16)f0.z; tw.h[3] = (bf16)f0.w;
        tw.h[4] = (bf16)f1.x; tw.h[5] = (bf16)f1.y; tw.h[6] = (bf16)f1.z; tw.h[7] = (bf16)f1.w;
        *(uint4*)&Bs[r][c * 16 + j * 8] = tw.u;
      }
    }
    __syncthreads();
    int kmax = (seg == 0) ? 128 : 64;
    for (int k0 = 0; k0 < kmax; k0 += 32) {
      bf16x8 a = *(const bf16x8*)&As[w * 16 + m][k0 + quad * 8];
#pragma unroll
      for (int t = 0; t < 4; ++t) {
        bf16x8 b = *(const bf16x8*)&Bs[t * 16 + m][k0 + quad * 8];
        acc[t] = __builtin_amdgcn_mfma_f32_16x16x32_bf16(a, b, acc[t], 0, 0, 0);
      }
    }
  }

#pragma unroll
  for (int t = 0; t < 4; ++t) {
    int o = t * 16 + m;
    float bv = fb1[o];
    float s = 0.f, q = 0.f;
#pragma unroll
    for (int r4 = 0; r4 < 4; ++r4) {
      int node = nbase + w * 16 + quad * 4 + r4;
      if (node < n) {
        float v = acc[t][r4] + bv;
        hf[(size_t)node * 64 + o] = (bf16)v;
        s += v;
        q += v * v;
      }
    }
    atomicAdd(&s_sum[o], s);
    atomicAdd(&s_sq[o], q);
  }
  __syncthreads();
  if (tid < 64) {
    atomicAdd(&stats[tid], s_sum[tid]);
    atomicAdd(&stats[64 + tid], s_sq[tid]);
  }
}

// ---------------- head ----------------
__global__ __launch_bounds__(256) void final_out_kernel(
    const bf16* __restrict__ hf, const float* __restrict__ st,
    const float* __restrict__ g, const float* __restrict__ be, float inv_n,
    const float* __restrict__ fw2, const float* __restrict__ fb2,
    float* __restrict__ out, int n) {
  int lane = threadIdx.x & 63;
  int node = blockIdx.x * 4 + (threadIdx.x >> 6);
  if (node >= n) return;
  float sc, sh;
  bn_coeffs(st, g, be, inv_n, lane, sc, sh);
  float v = (float)hf[(size_t)node * 64 + lane] * sc + sh;
  v = (v >= 0.f) ? v : 0.01f * v;
  v *= fw2[lane];
#pragma unroll
  for (int off = 32; off > 0; off >>= 1) v += __shfl_xor(v, off);
  if (lane == 0) out[node] = 1.f / (1.f + expf(-(v + fb2[0])));
}

extern "C" void kernel_launch(void* const* d_in, const int* in_sizes, int n_in,
                              void* d_out, int out_size, void* d_ws, size_t ws_size,
                              hipStream_t stream) {
  const int* node_deg = (const int*)d_in[0];
  const int* node_lab = (const int*)d_in[1];
  const int* ei = (const int*)d_in[2];
  const float* emb_deg = (const float*)d_in[3];
  const float* emb_lab = (const float*)d_in[4];
  const float* w0 = (const float*)d_in[5];
  const float* b0 = (const float*)d_in[6];
  const float* g0 = (const float*)d_in[7];
  const float* be0 = (const float*)d_in[8];
  const float* w1 = (const float*)d_in[9];
  const float* b1 = (const float*)d_in[10];
  const float* g1 = (const float*)d_in[11];
  const float* be1 = (const float*)d_in[12];
  const float* w2 = (const float*)d_in[13];
  const float* b2 = (const float*)d_in[14];
  const float* g2 = (const float*)d_in[15];
  const float* be2 = (const float*)d_in[16];
  const float* fw1 = (const float*)d_in[17];
  const float* fb1 = (const float*)d_in[18];
  const float* fg = (const float*)d_in[19];
  const float* fbe = (const float*)d_in[20];
  const float* fw2 = (const float*)d_in[21];
  const float* fb2 = (const float*)d_in[22];

  const int N = in_sizes[0];
  const int E = in_sizes[2] / 2;
  const int* src = ei;
  const int* dst = ei + E;
  const int NB = (N + 63) >> 6;
  const int CH = (E + NBLK - 1) / NBLK;
  const float inv_n = 1.0f / N;
  const int TN = (N + 3) / 4;  // src-tile width: 4 tiles x ~3.2MB of y each (fits 4MB XCD L2)

  char* ws = (char*)d_ws;
  size_t off = 0;
  auto alloc = [&](size_t bytes) {
    void* p = ws + off;
    off += (bytes + 255) & ~(size_t)255;
    return p;
  };
  bf16* z1 = (bf16*)alloc((size_t)N * 64 * 2);
  bf16* z2 = (bf16*)alloc((size_t)N * 64 * 2);
  bf16* h = (bf16*)alloc((size_t)N * 64 * 2);
  bf16* y = (bf16*)alloc((size_t)N * 64 * 2);  // reused as hf at the end
  int* packed = (int*)alloc((size_t)E * 4);
  int* colidx = (int*)alloc((size_t)E * 4);
  int* rowptr = (int*)alloc((size_t)(N + 1) * 4);
  int* splits = (int*)alloc((size_t)N * 4 * 4);  // per-node src-tile segment starts
  int* cnt = (int*)alloc((size_t)NBLK * NB * 4);
  int* woff = (int*)alloc((size_t)NBLK * NB * 4);
  int* btot = (int*)alloc((size_t)NB * 4);
  int* bucketptr = (int*)alloc((size_t)(NB + 1) * 4);
  float* stats = (float*)alloc(4 * 256 * 4);

  hipMemsetAsync(stats, 0, 4 * 256 * 4, stream);

  // CSR build (colidx grouped per node by src-tile; splits marks tile segments)
  bin_hist_kernel<<<NBLK, 256, 0, stream>>>(dst, cnt, E, CH, NB);
  bin_tot_kernel<<<(NB + 255) / 256, 256, 0, stream>>>(cnt, btot, NB);
  scan_buckets_kernel<<<1, 256, 0, stream>>>(btot, bucketptr, NB);
  bin_off_kernel<<<(NB + 255) / 256, 256, 0, stream>>>(cnt, bucketptr, woff, NB);
  bin_scatter_kernel<<<NBLK, 256, 0, stream>>>(src, dst, woff, packed, E, CH, NB);
  csr_finalize_kernel<<<NB, 256, 0, stream>>>(packed, bucketptr, rowptr, colidx, splits,
                                              N, E, TN);

  int ngrid = (N + 63) / 64;
  // gather: block = one 64-node bucket; 1563 blocks all co-resident -> soft
  // phase alignment across the grid without a barrier.

  // layer 0 (embedding fused into GEMM; x0 never materialized)
  mfma_gemm0<<<ngrid, 256, 0, stream>>>(node_deg, node_lab, emb_deg, emb_lab, w0, y, N);
  gather_kernel<<<NB, 256, 0, stream>>>(y, rowptr, splits, colidx, b0, h, stats, N);
  // layer 1
  mfma_gemm_bn<<<ngrid, 256, 0, stream>>>(h, stats, g0, be0, inv_n, w1, z1, y, N);
  gather_kernel<<<NB, 256, 0, stream>>>(y, rowptr, splits, colidx, b1, h, stats + 256, N);
  // layer 2
  mfma_gemm_bn<<<ngrid, 256, 0, stream>>>(h, stats + 256, g1, be1, inv_n, w2, z2, y, N);
  gather_kernel<<<NB, 256, 0, stream>>>(y, rowptr, splits, colidx, b2, h, stats + 512, N);
  // final MLP 320 -> 64 (embedding re-gathered inline)
  mfma_final<<<ngrid, 256, 0, stream>>>(node_deg, node_lab, emb_deg, emb_lab, z1, z2, h,
                                        stats + 512, g2, be2, inv_n, fw1, fb1, y,
                                        stats + 768, N);
  final_out_kernel<<<(N + 3) / 4, 256, 0, stream>>>(y, stats + 768, fg, fbe, inv_n,
                                                    fw2, fb2, (float*)d_out, N);
}

// Round 8
// 541.717 us; speedup vs baseline: 1.2340x; 1.2340x over previous
//
#include <hip/hip_runtime.h>
#include <math.h>

typedef __bf16 bf16;
typedef __attribute__((ext_vector_type(8))) __bf16 bf16x8;
typedef __attribute__((ext_vector_type(4))) float f32x4;

#define NBLK 128      // edge-partition blocks for binning (128 optimal: r13's 512 regressed)
#define NB_MAX 1600   // max buckets (N/64); N=100000 -> 1563

__device__ __forceinline__ void bn_coeffs(const float* st, const float* g,
                                          const float* be, float inv_n, int d,
                                          float& sc, float& sh) {
  float mean = st[d] * inv_n;
  float var = st[64 + d] * inv_n - mean * mean;
  sc = g[d] * rsqrtf(var + 1e-5f);
  sh = be[d] - mean * sc;
}

// ---------------- edge binning (bucket = dst>>6) ----------------
__global__ __launch_bounds__(256) void bin_hist_kernel(const int* __restrict__ dst,
                                                       int* __restrict__ cnt,
                                                       int E, int ch, int nb) {
  __shared__ int lcnt[NB_MAX];
  int tid = threadIdx.x, blk = blockIdx.x;
  for (int t = tid; t < nb; t += 256) lcnt[t] = 0;
  __syncthreads();
  int base = blk * ch, eend = min(E, base + ch);
  for (int e = base + tid; e < eend; e += 256) atomicAdd(&lcnt[dst[e] >> 6], 1);
  __syncthreads();
  for (int t = tid; t < nb; t += 256) cnt[blk * nb + t] = lcnt[t];
}

__global__ __launch_bounds__(256) void bin_tot_kernel(const int* __restrict__ cnt,
                                                      int* __restrict__ tot, int nb) {
  int b = blockIdx.x * 256 + threadIdx.x;
  if (b >= nb) return;
  int s = 0;
  for (int blk = 0; blk < NBLK; ++blk) s += cnt[blk * nb + b];
  tot[b] = s;
}

__global__ __launch_bounds__(256) void scan_buckets_kernel(const int* __restrict__ tot,
                                                           int* __restrict__ bucketptr, int nb) {
  __shared__ int lds[256];
  int tid = threadIdx.x;
  const int CH = 7;
  int vals[CH];
  int s = 0;
#pragma unroll
  for (int k = 0; k < CH; ++k) {
    int i = tid * CH + k;
    vals[k] = (i < nb) ? tot[i] : 0;
    s += vals[k];
  }
  lds[tid] = s;
  __syncthreads();
  for (int off = 1; off < 256; off <<= 1) {
    int v = (tid >= off) ? lds[tid - off] : 0;
    __syncthreads();
    lds[tid] += v;
    __syncthreads();
  }
  int run = lds[tid] - s;
  if (tid == 0) bucketptr[0] = 0;
#pragma unroll
  for (int k = 0; k < CH; ++k) {
    int i = tid * CH + k;
    run += vals[k];
    if (i < nb) bucketptr[i + 1] = run;
  }
}

__global__ __launch_bounds__(256) void bin_off_kernel(const int* __restrict__ cnt,
                                                      const int* __restrict__ bucketptr,
                                                      int* __restrict__ woff, int nb) {
  int b = blockIdx.x * 256 + threadIdx.x;
  if (b >= nb) return;
  int run = bucketptr[b];
  for (int blk = 0; blk < NBLK; ++blk) {
    woff[blk * nb + b] = run;
    run += cnt[blk * nb + b];
  }
}

__global__ __launch_bounds__(256) void bin_scatter_kernel(const int* __restrict__ src,
                                                          const int* __restrict__ dst,
                                                          const int* __restrict__ woff,
                                                          int* __restrict__ packed,
                                                          int E, int ch, int nb) {
  __shared__ int cur[NB_MAX];
  int tid = threadIdx.x, blk = blockIdx.x;
  for (int t = tid; t < nb; t += 256) cur[t] = woff[blk * nb + t];
  __syncthreads();
  int base = blk * ch, eend = min(E, base + ch);
  for (int e = base + tid; e < eend; e += 256) {
    int d = dst[e], s = src[e];
    int pos = atomicAdd(&cur[d >> 6], 1);
    packed[pos] = ((d & 63) << 17) | s;
  }
}

__global__ __launch_bounds__(256) void csr_finalize_kernel(
    const int* __restrict__ packed, const int* __restrict__ bucketptr,
    int* __restrict__ rowptr, int* __restrict__ colidx, int n, int E) {
  __shared__ int hist[64], offs[64];
  int tid = threadIdx.x, b = blockIdx.x;
  if (tid < 64) hist[tid] = 0;
  __syncthreads();
  int beg = bucketptr[b], end = bucketptr[b + 1];
  for (int e = beg + tid; e < end; e += 256) atomicAdd(&hist[packed[e] >> 17], 1);
  __syncthreads();
  if (tid == 0) {
    int run = 0;
    for (int j = 0; j < 64; ++j) { offs[j] = run; run += hist[j]; }
  }
  __syncthreads();
  if (tid < 64) {
    int idx = b * 64 + tid;
    if (idx < n) rowptr[idx] = beg + offs[tid];
    hist[tid] = offs[tid];
  }
  if (b == 0 && tid == 64) rowptr[n] = E;
  __syncthreads();
  for (int e = beg + tid; e < end; e += 256) {
    int w = packed[e];
    int pos = atomicAdd(&hist[w >> 17], 1);
    colidx[beg + pos] = w & 0x1FFFF;
  }
}

// ------- MFMA GEMM 0 with fused embedding (no x0 materialization) -------
__global__ __launch_bounds__(256) void mfma_gemm0(
    const int* __restrict__ deg, const int* __restrict__ lab,
    const float* __restrict__ ed, const float* __restrict__ el,
    const float* __restrict__ W, bf16* __restrict__ y, int n) {
  __shared__ bf16 As[64][136];
  __shared__ bf16 Bs[64][136];
  int tid = threadIdx.x;
  int nbase = blockIdx.x * 64;
  {
    int r = tid >> 2, c = tid & 3;
    int node = nbase + r;
    union { bf16 hh[32]; uint4 u[4]; } t;
    if (node < n) {
      int idx = (c < 2) ? deg[node] : lab[node];
      const float* srcp = (c < 2) ? (ed + (size_t)idx * 64 + c * 32)
                                  : (el + (size_t)idx * 64 + (c - 2) * 32);
#pragma unroll
      for (int j = 0; j < 8; ++j) {
        float4 f = ((const float4*)srcp)[j];
        t.hh[j * 4 + 0] = (bf16)f.x; t.hh[j * 4 + 1] = (bf16)f.y;
        t.hh[j * 4 + 2] = (bf16)f.z; t.hh[j * 4 + 3] = (bf16)f.w;
      }
    } else {
#pragma unroll
      for (int j = 0; j < 4; ++j) t.u[j] = uint4{0, 0, 0, 0};
    }
#pragma unroll
    for (int j = 0; j < 4; ++j) *(uint4*)&As[r][c * 32 + j * 8] = t.u[j];
    const float4* wp = (const float4*)(W + r * 128 + c * 32);
#pragma unroll
    for (int j = 0; j < 4; ++j) {
      float4 f0 = wp[j * 2], f1 = wp[j * 2 + 1];
      union { bf16 h[8]; uint4 u; } tw;
      tw.h[0] = (bf16)f0.x; tw.h[1] = (bf16)f0.y; tw.h[2] = (bf16)f0.z; tw.h[3] = (bf16)f0.w;
      tw.h[4] = (bf16)f1.x; tw.h[5] = (bf16)f1.y; tw.h[6] = (bf16)f1.z; tw.h[7] = (bf16)f1.w;
      *(uint4*)&Bs[r][c * 32 + j * 8] = tw.u;
    }
  }
  __syncthreads();
  int l = tid & 63, w = tid >> 6, m = l & 15, quad = l >> 4;
  f32x4 acc[4] = {{0.f, 0.f, 0.f, 0.f}, {0.f, 0.f, 0.f, 0.f},
                  {0.f, 0.f, 0.f, 0.f}, {0.f, 0.f, 0.f, 0.f}};
#pragma unroll
  for (int k0 = 0; k0 < 128; k0 += 32) {
    bf16x8 a = *(const bf16x8*)&As[w * 16 + m][k0 + quad * 8];
#pragma unroll
    for (int t = 0; t < 4; ++t) {
      bf16x8 b = *(const bf16x8*)&Bs[t * 16 + m][k0 + quad * 8];
      acc[t] = __builtin_amdgcn_mfma_f32_16x16x32_bf16(a, b, acc[t], 0, 0, 0);
    }
  }
#pragma unroll
  for (int t = 0; t < 4; ++t)
#pragma unroll
    for (int r4 = 0; r4 < 4; ++r4) {
      int node = nbase + w * 16 + quad * 4 + r4;
      if (node < n) y[(size_t)node * 64 + t * 16 + m] = (bf16)acc[t][r4];
    }
}

// ------- MFMA GEMM (layers 1,2) -------
__global__ __launch_bounds__(256) void mfma_gemm_bn(
    const bf16* __restrict__ hin, const float* __restrict__ st,
    const float* __restrict__ g, const float* __restrict__ be, float inv_n,
    const float* __restrict__ W, bf16* __restrict__ z,
    bf16* __restrict__ y, int n) {
  __shared__ bf16 As[64][72];
  __shared__ bf16 Bs[64][72];
  __shared__ float ssc[64], ssh[64];
  int tid = threadIdx.x;
  int nbase = blockIdx.x * 64;
  if (tid < 64) {
    float sc, sh;
    bn_coeffs(st, g, be, inv_n, tid, sc, sh);
    ssc[tid] = sc; ssh[tid] = sh;
  }
  __syncthreads();
  {
    int r = tid >> 2, c = tid & 3;
    int node = nbase + r;
    union { bf16 h[16]; uint4 u[2]; } t;
    if (node < n) {
      const uint4* p = (const uint4*)(hin + (size_t)node * 64 + c * 16);
      union { uint4 u; bf16 h[8]; } a0, a1;
      a0.u = p[0]; a1.u = p[1];
#pragma unroll
      for (int j = 0; j < 8; ++j) {
        int d = c * 16 + j;
        float v = (float)a0.h[j] * ssc[d] + ssh[d];
        v = (v >= 0.f) ? v : 0.01f * v;
        t.h[j] = (bf16)v;
      }
#pragma unroll
      for (int j = 0; j < 8; ++j) {
        int d = c * 16 + 8 + j;
        float v = (float)a1.h[j] * ssc[d] + ssh[d];
        v = (v >= 0.f) ? v : 0.01f * v;
        t.h[8 + j] = (bf16)v;
      }
      *(uint4*)(z + (size_t)node * 64 + c * 16) = t.u[0];
      *(uint4*)(z + (size_t)node * 64 + c * 16 + 8) = t.u[1];
    } else {
      t.u[0] = uint4{0, 0, 0, 0}; t.u[1] = uint4{0, 0, 0, 0};
    }
    *(uint4*)&As[r][c * 16] = t.u[0];
    *(uint4*)&As[r][c * 16 + 8] = t.u[1];
    const float4* wp = (const float4*)(W + r * 64 + c * 16);
#pragma unroll
    for (int j = 0; j < 2; ++j) {
      float4 f0 = wp[j * 2], f1 = wp[j * 2 + 1];
      union { bf16 h[8]; uint4 u; } tw;
      tw.h[0] = (bf16)f0.x; tw.h[1] = (bf16)f0.y; tw.h[2] = (bf16)f0.z; tw.h[3] = (bf16)f0.w;
      tw.h[4] = (bf16)f1.x; tw.h[5] = (bf16)f1.y; tw.h[6] = (bf16)f1.z; tw.h[7] = (bf16)f1.w;
      *(uint4*)&Bs[r][c * 16 + j * 8] = tw.u;
    }
  }
  __syncthreads();
  int l = tid & 63, w = tid >> 6, m = l & 15, quad = l >> 4;
  f32x4 acc[4] = {{0.f, 0.f, 0.f, 0.f}, {0.f, 0.f, 0.f, 0.f},
                  {0.f, 0.f, 0.f, 0.f}, {0.f, 0.f, 0.f, 0.f}};
#pragma unroll
  for (int k0 = 0; k0 < 64; k0 += 32) {
    bf16x8 a = *(const bf16x8*)&As[w * 16 + m][k0 + quad * 8];
#pragma unroll
    for (int t = 0; t < 4; ++t) {
      bf16x8 b = *(const bf16x8*)&Bs[t * 16 + m][k0 + quad * 8];
      acc[t] = __builtin_amdgcn_mfma_f32_16x16x32_bf16(a, b, acc[t], 0, 0, 0);
    }
  }
#pragma unroll
  for (int t = 0; t < 4; ++t)
#pragma unroll
    for (int r4 = 0; r4 < 4; ++r4) {
      int node = nbase + w * 16 + quad * 4 + r4;
      if (node < n) y[(size_t)node * 64 + t * 16 + m] = (bf16)acc[t][r4];
    }
}

// ------- gather v8: v5 engine + colidx software pipeline -------
// v5's 4-node/16-lane/uint2 layout (proven best clean: 80.5us, VGPR 32).
// NEW: the colidx->y two-hop dependent chain is split. Prologue preloads the
// first 8 colidx per node (address-clamped to E-1, UNCONDITIONAL loads -- no
// predication in the address path, the v2/v7 lesson). Each main trip issues
// the NEXT trip's 8 colidx loads alongside the current trip's 8 y loads, then
// rotates. Steady-state critical path = y-load latency only; colidx latency
// fully hidden under the previous trip. Mid-trip consumes the prefetched
// s0..s3 (registers are always colidx[e..e+7] clamped after the main loop).
__global__ __launch_bounds__(256, 4) void gather_kernel(
    const bf16* __restrict__ y, const int* __restrict__ rowptr,
    const int* __restrict__ colidx, const float* __restrict__ bias,
    bf16* __restrict__ h, float* __restrict__ stats, int n, int E) {
  __shared__ float s_sum[64], s_sq[64];
  int tid = threadIdx.x;
  if (tid < 64) { s_sum[tid] = 0.f; s_sq[tid] = 0.f; }
  __syncthreads();
  int lane = tid & 63, wv = tid >> 6;
  int g = lane >> 4, lh = lane & 15;
  const uint2* y2 = (const uint2*)y;
  uint2* h2 = (uint2*)h;
  float b0 = bias[4 * lh + 0], b1 = bias[4 * lh + 1];
  float b2 = bias[4 * lh + 2], b3 = bias[4 * lh + 3];
  float p0 = 0.f, p1 = 0.f, p2 = 0.f, p3 = 0.f;
  float q0 = 0.f, q1 = 0.f, q2 = 0.f, q3 = 0.f;
  int stride = gridDim.x * 16;
  int emax = E - 1;

#define ACC4(d)                                                      \
  {                                                                  \
    union { unsigned u; float f; } t_;                               \
    t_.u = (d).x << 16;         a0 += t_.f;                          \
    t_.u = (d).x & 0xFFFF0000u; a1 += t_.f;                          \
    t_.u = (d).y << 16;         a2 += t_.f;                          \
    t_.u = (d).y & 0xFFFF0000u; a3 += t_.f;                          \
  }

  for (int nb = (blockIdx.x * 4 + wv) * 4; nb < n; nb += stride) {
    int node = nb + g;
    bool valid = node < n;
    int e = valid ? rowptr[node] : 0;
    int f = valid ? rowptr[node + 1] : 0;
    float a0 = 0.f, a1 = 0.f, a2 = 0.f, a3 = 0.f;
    // prologue: preload first 8 colidx (clamped, unconditional)
    int s0 = colidx[min(e + 0, emax)], s1 = colidx[min(e + 1, emax)];
    int s2 = colidx[min(e + 2, emax)], s3 = colidx[min(e + 3, emax)];
    int s4 = colidx[min(e + 4, emax)], s5 = colidx[min(e + 5, emax)];
    int s6 = colidx[min(e + 6, emax)], s7 = colidx[min(e + 7, emax)];
    // main: 8 edges per trip; y loads use the PRELOADED s*, next trip's
    // colidx issues in parallel with them.
    for (;;) {
      bool a = (e + 8 <= f);
      if (__ballot(a) == 0ull) break;
      if (a) {
        uint2 d0 = y2[(size_t)s0 * 16 + lh];
        uint2 d1 = y2[(size_t)s1 * 16 + lh];
        uint2 d2 = y2[(size_t)s2 * 16 + lh];
        uint2 d3 = y2[(size_t)s3 * 16 + lh];
        uint2 d4 = y2[(size_t)s4 * 16 + lh];
        uint2 d5 = y2[(size_t)s5 * 16 + lh];
        uint2 d6 = y2[(size_t)s6 * 16 + lh];
        uint2 d7 = y2[(size_t)s7 * 16 + lh];
        int t0 = colidx[min(e + 8, emax)], t1 = colidx[min(e + 9, emax)];
        int t2 = colidx[min(e + 10, emax)], t3 = colidx[min(e + 11, emax)];
        int t4 = colidx[min(e + 12, emax)], t5 = colidx[min(e + 13, emax)];
        int t6 = colidx[min(e + 14, emax)], t7 = colidx[min(e + 15, emax)];
        ACC4(d0); ACC4(d1); ACC4(d2); ACC4(d3);
        ACC4(d4); ACC4(d5); ACC4(d6); ACC4(d7);
        s0 = t0; s1 = t1; s2 = t2; s3 = t3;
        s4 = t4; s5 = t5; s6 = t6; s7 = t7;
        e += 8;
      }
    }
    // mid: one 4-edge trip using the prefetched s0..s3 (valid: s* always
    // holds colidx[e..e+7] clamped at this point)
    {
      bool a = (e + 4 <= f);
      if (__ballot(a) != 0ull) {
        if (a) {
          uint2 d0 = y2[(size_t)s0 * 16 + lh];
          uint2 d1 = y2[(size_t)s1 * 16 + lh];
          uint2 d2 = y2[(size_t)s2 * 16 + lh];
          uint2 d3 = y2[(size_t)s3 * 16 + lh];
          ACC4(d0); ACC4(d1); ACC4(d2); ACC4(d3);
          e += 4;
        }
      }
    }
    // tail: up to 3 predicated single-edge steps (direct loads, as v5)
#pragma unroll
    for (int t = 0; t < 3; ++t) {
      bool a = e < f;
      if (a) {
        int s = colidx[e];
        uint2 d = y2[(size_t)s * 16 + lh];
        ACC4(d);
        ++e;
      }
    }
    if (valid) {
      uint2 sd = y2[(size_t)node * 16 + lh];
      float s0f, s1f, s2f, s3f;
      {
        union { unsigned u; float f; } t_;
        t_.u = sd.x << 16;         s0f = t_.f;
        t_.u = sd.x & 0xFFFF0000u; s1f = t_.f;
        t_.u = sd.y << 16;         s2f = t_.f;
        t_.u = sd.y & 0xFFFF0000u; s3f = t_.f;
      }
      float v0 = a0 + s0f + b0;
      float v1 = a1 + s1f + b1;
      float v2 = a2 + s2f + b2;
      float v3 = a3 + s3f + b3;
      union { bf16 hh[4]; uint2 u; } o;
      o.hh[0] = (bf16)v0; o.hh[1] = (bf16)v1;
      o.hh[2] = (bf16)v2; o.hh[3] = (bf16)v3;
      h2[(size_t)node * 16 + lh] = o.u;
      p0 += v0; q0 += v0 * v0;
      p1 += v1; q1 += v1 * v1;
      p2 += v2; q2 += v2 * v2;
      p3 += v3; q3 += v3 * v3;
    }
  }
#undef ACC4
  atomicAdd(&s_sum[4 * lh + 0], p0); atomicAdd(&s_sq[4 * lh + 0], q0);
  atomicAdd(&s_sum[4 * lh + 1], p1); atomicAdd(&s_sq[4 * lh + 1], q1);
  atomicAdd(&s_sum[4 * lh + 2], p2); atomicAdd(&s_sq[4 * lh + 2], q2);
  atomicAdd(&s_sum[4 * lh + 3], p3); atomicAdd(&s_sq[4 * lh + 3], q3);
  __syncthreads();
  if (tid < 64) {
    atomicAdd(&stats[tid], s_sum[tid]);
    atomicAdd(&stats[64 + tid], s_sq[tid]);
  }
}

// ------- final MLP over concat [emb(deg,lab)|z1|z2|bnleaky(h2)] (320 -> 64), MFMA -------
__global__ __launch_bounds__(256) void mfma_final(
    const int* __restrict__ deg, const int* __restrict__ lab,
    const float* __restrict__ ed, const float* __restrict__ el,
    const bf16* __restrict__ z1, const bf16* __restrict__ z2,
    const bf16* __restrict__ h2, const float* __restrict__ st2,
    const float* __restrict__ g2, const float* __restrict__ be2, float inv_n,
    const float* __restrict__ fw1, const float* __restrict__ fb1,
    bf16* __restrict__ hf, float* __restrict__ stats, int n) {
  __shared__ bf16 As[64][136];
  __shared__ bf16 Bs[64][136];
  __shared__ float s_sum[64], s_sq[64], ssc[64], ssh[64];
  int tid = threadIdx.x;
  if (tid < 64) {
    s_sum[tid] = 0.f; s_sq[tid] = 0.f;
    float sc, sh;
    bn_coeffs(st2, g2, be2, inv_n, tid, sc, sh);
    ssc[tid] = sc; ssh[tid] = sh;
  }
  int nbase = blockIdx.x * 64;
  int l = tid & 63, w = tid >> 6, m = l & 15, quad = l >> 4;
  int r = tid >> 2, c = tid & 3;
  int node_r = nbase + r;
  f32x4 acc[4] = {{0.f, 0.f, 0.f, 0.f}, {0.f, 0.f, 0.f, 0.f},
                  {0.f, 0.f, 0.f, 0.f}, {0.f, 0.f, 0.f, 0.f}};

#pragma unroll
  for (int seg = 0; seg < 4; ++seg) {
    __syncthreads();
    if (seg == 0) {
      union { bf16 hh[32]; uint4 u[4]; } t;
      if (node_r < n) {
        int idx = (c < 2) ? deg[node_r] : lab[node_r];
        const float* srcp = (c < 2) ? (ed + (size_t)idx * 64 + c * 32)
                                    : (el + (size_t)idx * 64 + (c - 2) * 32);
#pragma unroll
        for (int j = 0; j < 8; ++j) {
          float4 f = ((const float4*)srcp)[j];
          t.hh[j * 4 + 0] = (bf16)f.x; t.hh[j * 4 + 1] = (bf16)f.y;
          t.hh[j * 4 + 2] = (bf16)f.z; t.hh[j * 4 + 3] = (bf16)f.w;
        }
      } else {
#pragma unroll
        for (int j = 0; j < 4; ++j) t.u[j] = uint4{0, 0, 0, 0};
      }
#pragma unroll
      for (int j = 0; j < 4; ++j) *(uint4*)&As[r][c * 32 + j * 8] = t.u[j];
      const float4* wp = (const float4*)(fw1 + r * 320 + c * 32);
#pragma unroll
      for (int j = 0; j < 4; ++j) {
        float4 f0 = wp[j * 2], f1 = wp[j * 2 + 1];
        union { bf16 h[8]; uint4 u; } tw;
        tw.h[0] = (bf16)f0.x; tw.h[1] = (bf16)f0.y; tw.h[2] = (bf16)f0.z; tw.h[3] = (bf16)f0.w;
        tw.h[4] = (bf16)f1.x; tw.h[5] = (bf16)f1.y; tw.h[6] = (bf16)f1.z; tw.h[7] = (bf16)f1.w;
        *(uint4*)&Bs[r][c * 32 + j * 8] = tw.u;
      }
    } else if (seg < 3) {
      const bf16* zz = (seg == 1) ? z1 : z2;
      uint4 v[2] = {};
      if (node_r < n) {
        const uint4* p = (const uint4*)(zz + (size_t)node_r * 64 + c * 16);
        v[0] = p[0]; v[1] = p[1];
      }
      *(uint4*)&As[r][c * 16] = v[0];
      *(uint4*)&As[r][c * 16 + 8] = v[1];
      const float4* wp = (const float4*)(fw1 + r * 320 + (seg == 1 ? 128 : 192) + c * 16);
#pragma unroll
      for (int j = 0; j < 2; ++j) {
        float4 f0 = wp[j * 2], f1 = wp[j * 2 + 1];
        union { bf16 h[8]; uint4 u; } t;
        t.h[0] = (bf16)f0.x; t.h[1] = (bf16)f0.y; t.h[2] = (bf16)f0.z; t.h[3] = (bf16)f0.w;
        t.h[4] = (bf16)f1.x; t.h[5] = (bf16)f1.y; t.h[6] = (bf16)f1.z; t.h[7] = (bf16)f1.w;
        *(uint4*)&Bs[r][c * 16 + j * 8] = t.u;
      }
    } else {
      union { bf16 h[16]; uint4 u[2]; } t;
      if (node_r < n) {
        const uint4* p = (const uint4*)(h2 + (size_t)node_r * 64 + c * 16);
        union { uint4 u; bf16 h[8]; } a0, a1;
        a0.u = p[0]; a1.u = p[1];
#pragma unroll
        for (int j = 0; j < 8; ++j) {
          int d = c * 16 + j;
          float v = (float)a0.h[j] * ssc[d] + ssh[d];
          v = (v >= 0.f) ? v : 0.01f * v;
          t.h[j] = (bf16)v;
        }
#pragma unroll
        for (int j = 0; j < 8; ++j) {
          int d = c * 16 + 8 + j;
          float v = (float)a1.h[j] * ssc[d] + ssh[d];
          v = (v >= 0.f) ? v : 0.01f * v;
          t.h[8 + j] = (bf16)v;
        }
      } else {
        t.u[0] = uint4{0, 0, 0, 0}; t.u[1] = uint4{0, 0, 0, 0};
      }
      *(uint4*)&As[r][c * 16] = t.u[0];
      *(uint4*)&As[r][c * 16 + 8] = t.u[1];
      const float4* wp = (const float4*)(fw1 + r * 320 + 256 + c * 16);
#pragma unroll
      for (int j = 0; j < 2; ++j) {
        float4 f0 = wp[j * 2], f1 = wp[j * 2 + 1];
        union { bf16 h[8]; uint4 u; } tw;
        tw.h[0] = (bf16)f0.x; tw.h[1] = (bf16)f0.y; tw.h[2] = (bf16)f0.z; tw.h[3] = (bf16)f0.w;
        tw.h[4] = (bf16)f1.x; tw.h[5] = (bf16)f1.y; tw.h[6] = (bf16)f1.z; tw.h[7] = (bf16)f1.w;
        *(uint4*)&Bs[r][c * 16 + j * 8] = tw.u;
      }
    }
    __syncthreads();
    int kmax = (seg == 0) ? 128 : 64;
    for (int k0 = 0; k0 < kmax; k0 += 32) {
      bf16x8 a = *(const bf16x8*)&As[w * 16 + m][k0 + quad * 8];
#pragma unroll
      for (int t = 0; t < 4; ++t) {
        bf16x8 b = *(const bf16x8*)&Bs[t * 16 + m][k0 + quad * 8];
        acc[t] = __builtin_amdgcn_mfma_f32_16x16x32_bf16(a, b, acc[t], 0, 0, 0);
      }
    }
  }

#pragma unroll
  for (int t = 0; t < 4; ++t) {
    int o = t * 16 + m;
    float bv = fb1[o];
    float s = 0.f, q = 0.f;
#pragma unroll
    for (int r4 = 0; r4 < 4; ++r4) {
      int node = nbase + w * 16 + quad * 4 + r4;
      if (node < n) {
        float v = acc[t][r4] + bv;
        hf[(size_t)node * 64 + o] = (bf16)v;
        s += v;
        q += v * v;
      }
    }
    atomicAdd(&s_sum[o], s);
    atomicAdd(&s_sq[o], q);
  }
  __syncthreads();
  if (tid < 64) {
    atomicAdd(&stats[tid], s_sum[tid]);
    atomicAdd(&stats[64 + tid], s_sq[tid]);
  }
}

// ---------------- head ----------------
__global__ __launch_bounds__(256) void final_out_kernel(
    const bf16* __restrict__ hf, const float* __restrict__ st,
    const float* __restrict__ g, const float* __restrict__ be, float inv_n,
    const float* __restrict__ fw2, const float* __restrict__ fb2,
    float* __restrict__ out, int n) {
  int lane = threadIdx.x & 63;
  int node = blockIdx.x * 4 + (threadIdx.x >> 6);
  if (node >= n) return;
  float sc, sh;
  bn_coeffs(st, g, be, inv_n, lane, sc, sh);
  float v = (float)hf[(size_t)node * 64 + lane] * sc + sh;
  v = (v >= 0.f) ? v : 0.01f * v;
  v *= fw2[lane];
#pragma unroll
  for (int off = 32; off > 0; off >>= 1) v += __shfl_xor(v, off);
  if (lane == 0) out[node] = 1.f / (1.f + expf(-(v + fb2[0])));
}

extern "C" void kernel_launch(void* const* d_in, const int* in_sizes, int n_in,
                              void* d_out, int out_size, void* d_ws, size_t ws_size,
                              hipStream_t stream) {
  const int* node_deg = (const int*)d_in[0];
  const int* node_lab = (const int*)d_in[1];
  const int* ei = (const int*)d_in[2];
  const float* emb_deg = (const float*)d_in[3];
  const float* emb_lab = (const float*)d_in[4];
  const float* w0 = (const float*)d_in[5];
  const float* b0 = (const float*)d_in[6];
  const float* g0 = (const float*)d_in[7];
  const float* be0 = (const float*)d_in[8];
  const float* w1 = (const float*)d_in[9];
  const float* b1 = (const float*)d_in[10];
  const float* g1 = (const float*)d_in[11];
  const float* be1 = (const float*)d_in[12];
  const float* w2 = (const float*)d_in[13];
  const float* b2 = (const float*)d_in[14];
  const float* g2 = (const float*)d_in[15];
  const float* be2 = (const float*)d_in[16];
  const float* fw1 = (const float*)d_in[17];
  const float* fb1 = (const float*)d_in[18];
  const float* fg = (const float*)d_in[19];
  const float* fbe = (const float*)d_in[20];
  const float* fw2 = (const float*)d_in[21];
  const float* fb2 = (const float*)d_in[22];

  const int N = in_sizes[0];
  const int E = in_sizes[2] / 2;
  const int* src = ei;
  const int* dst = ei + E;
  const int NB = (N + 63) >> 6;
  const int CH = (E + NBLK - 1) / NBLK;
  const float inv_n = 1.0f / N;

  char* ws = (char*)d_ws;
  size_t off = 0;
  auto alloc = [&](size_t bytes) {
    void* p = ws + off;
    off += (bytes + 255) & ~(size_t)255;
    return p;
  };
  bf16* z1 = (bf16*)alloc((size_t)N * 64 * 2);
  bf16* z2 = (bf16*)alloc((size_t)N * 64 * 2);
  bf16* h = (bf16*)alloc((size_t)N * 64 * 2);
  bf16* y = (bf16*)alloc((size_t)N * 64 * 2);  // reused as hf at the end
  int* packed = (int*)alloc((size_t)E * 4);
  int* colidx = (int*)alloc((size_t)E * 4);
  int* rowptr = (int*)alloc((size_t)(N + 1) * 4);
  int* cnt = (int*)alloc((size_t)NBLK * NB * 4);
  int* woff = (int*)alloc((size_t)NBLK * NB * 4);
  int* btot = (int*)alloc((size_t)NB * 4);
  int* bucketptr = (int*)alloc((size_t)(NB + 1) * 4);
  float* stats = (float*)alloc(4 * 256 * 4);

  hipMemsetAsync(stats, 0, 4 * 256 * 4, stream);

  // CSR build
  bin_hist_kernel<<<NBLK, 256, 0, stream>>>(dst, cnt, E, CH, NB);
  bin_tot_kernel<<<(NB + 255) / 256, 256, 0, stream>>>(cnt, btot, NB);
  scan_buckets_kernel<<<1, 256, 0, stream>>>(btot, bucketptr, NB);
  bin_off_kernel<<<(NB + 255) / 256, 256, 0, stream>>>(cnt, bucketptr, woff, NB);
  bin_scatter_kernel<<<NBLK, 256, 0, stream>>>(src, dst, woff, packed, E, CH, NB);
  csr_finalize_kernel<<<NB, 256, 0, stream>>>(packed, bucketptr, rowptr, colidx, N, E);

  int ngrid = (N + 63) / 64;
  // gather: 4 nodes/wave x 4 waves = 16 nodes/block/sweep; 2048 blocks,
  // grid-stride covers N in ~3 sweeps (v5-proven config).
  int ggrid = 2048;

  // layer 0 (embedding fused into GEMM; x0 never materialized)
  mfma_gemm0<<<ngrid, 256, 0, stream>>>(node_deg, node_lab, emb_deg, emb_lab, w0, y, N);
  gather_kernel<<<ggrid, 256, 0, stream>>>(y, rowptr, colidx, b0, h, stats, N, E);
  // layer 1
  mfma_gemm_bn<<<ngrid, 256, 0, stream>>>(h, stats, g0, be0, inv_n, w1, z1, y, N);
  gather_kernel<<<ggrid, 256, 0, stream>>>(y, rowptr, colidx, b1, h, stats + 256, N, E);
  // layer 2
  mfma_gemm_bn<<<ngrid, 256, 0, stream>>>(h, stats + 256, g1, be1, inv_n, w2, z2, y, N);
  gather_kernel<<<ggrid, 256, 0, stream>>>(y, rowptr, colidx, b2, h, stats + 512, N, E);
  // final MLP 320 -> 64 (embedding re-gathered inline)
  mfma_final<<<ngrid, 256, 0, stream>>>(node_deg, node_lab, emb_deg, emb_lab, z1, z2, h,
                                        stats + 512, g2, be2, inv_n, fw1, fb1, y,
                                        stats + 768, N);
  final_out_kernel<<<(N + 3) / 4, 256, 0, stream>>>(y, stats + 768, fg, fbe, inv_n,
                                                    fw2, fb2, (float*)d_out, N);
}

// Round 9
// 521.422 us; speedup vs baseline: 1.2820x; 1.0389x over previous
//
#include <hip/hip_runtime.h>
#include <math.h>

typedef __bf16 bf16;
typedef __attribute__((ext_vector_type(8))) __bf16 bf16x8;
typedef __attribute__((ext_vector_type(4))) float f32x4;

#define NBLK 128      // edge-partition blocks for binning (128 optimal: r13's 512 regressed)
#define NB_MAX 1600   // max buckets (N/64); N=100000 -> 1563

__device__ __forceinline__ void bn_coeffs(const float* st, const float* g,
                                          const float* be, float inv_n, int d,
                                          float& sc, float& sh) {
  float mean = st[d] * inv_n;
  float var = st[64 + d] * inv_n - mean * mean;
  sc = g[d] * rsqrtf(var + 1e-5f);
  sh = be[d] - mean * sc;
}

// ---------------- edge binning (bucket = dst>>6) ----------------
__global__ __launch_bounds__(256) void bin_hist_kernel(const int* __restrict__ dst,
                                                       int* __restrict__ cnt,
                                                       int E, int ch, int nb) {
  __shared__ int lcnt[NB_MAX];
  int tid = threadIdx.x, blk = blockIdx.x;
  for (int t = tid; t < nb; t += 256) lcnt[t] = 0;
  __syncthreads();
  int base = blk * ch, eend = min(E, base + ch);
  for (int e = base + tid; e < eend; e += 256) atomicAdd(&lcnt[dst[e] >> 6], 1);
  __syncthreads();
  for (int t = tid; t < nb; t += 256) cnt[blk * nb + t] = lcnt[t];
}

__global__ __launch_bounds__(256) void bin_tot_kernel(const int* __restrict__ cnt,
                                                      int* __restrict__ tot, int nb) {
  int b = blockIdx.x * 256 + threadIdx.x;
  if (b >= nb) return;
  int s = 0;
  for (int blk = 0; blk < NBLK; ++blk) s += cnt[blk * nb + b];
  tot[b] = s;
}

__global__ __launch_bounds__(256) void scan_buckets_kernel(const int* __restrict__ tot,
                                                           int* __restrict__ bucketptr, int nb) {
  __shared__ int lds[256];
  int tid = threadIdx.x;
  const int CH = 7;
  int vals[CH];
  int s = 0;
#pragma unroll
  for (int k = 0; k < CH; ++k) {
    int i = tid * CH + k;
    vals[k] = (i < nb) ? tot[i] : 0;
    s += vals[k];
  }
  lds[tid] = s;
  __syncthreads();
  for (int off = 1; off < 256; off <<= 1) {
    int v = (tid >= off) ? lds[tid - off] : 0;
    __syncthreads();
    lds[tid] += v;
    __syncthreads();
  }
  int run = lds[tid] - s;
  if (tid == 0) bucketptr[0] = 0;
#pragma unroll
  for (int k = 0; k < CH; ++k) {
    int i = tid * CH + k;
    run += vals[k];
    if (i < nb) bucketptr[i + 1] = run;
  }
}

__global__ __launch_bounds__(256) void bin_off_kernel(const int* __restrict__ cnt,
                                                      const int* __restrict__ bucketptr,
                                                      int* __restrict__ woff, int nb) {
  int b = blockIdx.x * 256 + threadIdx.x;
  if (b >= nb) return;
  int run = bucketptr[b];
  for (int blk = 0; blk < NBLK; ++blk) {
    woff[blk * nb + b] = run;
    run += cnt[blk * nb + b];
  }
}

__global__ __launch_bounds__(256) void bin_scatter_kernel(const int* __restrict__ src,
                                                          const int* __restrict__ dst,
                                                          const int* __restrict__ woff,
                                                          int* __restrict__ packed,
                                                          int E, int ch, int nb) {
  __shared__ int cur[NB_MAX];
  int tid = threadIdx.x, blk = blockIdx.x;
  for (int t = tid; t < nb; t += 256) cur[t] = woff[blk * nb + t];
  __syncthreads();
  int base = blk * ch, eend = min(E, base + ch);
  for (int e = base + tid; e < eend; e += 256) {
    int d = dst[e], s = src[e];
    int pos = atomicAdd(&cur[d >> 6], 1);
    packed[pos] = ((d & 63) << 17) | s;
  }
}

__global__ __launch_bounds__(256) void csr_finalize_kernel(
    const int* __restrict__ packed, const int* __restrict__ bucketptr,
    int* __restrict__ rowptr, int* __restrict__ colidx, int n, int E) {
  __shared__ int hist[64], offs[64];
  int tid = threadIdx.x, b = blockIdx.x;
  if (tid < 64) hist[tid] = 0;
  __syncthreads();
  int beg = bucketptr[b], end = bucketptr[b + 1];
  for (int e = beg + tid; e < end; e += 256) atomicAdd(&hist[packed[e] >> 17], 1);
  __syncthreads();
  if (tid == 0) {
    int run = 0;
    for (int j = 0; j < 64; ++j) { offs[j] = run; run += hist[j]; }
  }
  __syncthreads();
  if (tid < 64) {
    int idx = b * 64 + tid;
    if (idx < n) rowptr[idx] = beg + offs[tid];
    hist[tid] = offs[tid];
  }
  if (b == 0 && tid == 64) rowptr[n] = E;
  __syncthreads();
  for (int e = beg + tid; e < end; e += 256) {
    int w = packed[e];
    int pos = atomicAdd(&hist[w >> 17], 1);
    colidx[beg + pos] = w & 0x1FFFF;
  }
}

// ------- MFMA GEMM 0 with fused embedding (no x0 materialization) -------
__global__ __launch_bounds__(256) void mfma_gemm0(
    const int* __restrict__ deg, const int* __restrict__ lab,
    const float* __restrict__ ed, const float* __restrict__ el,
    const float* __restrict__ W, bf16* __restrict__ y, int n) {
  __shared__ bf16 As[64][136];
  __shared__ bf16 Bs[64][136];
  int tid = threadIdx.x;
  int nbase = blockIdx.x * 64;
  {
    int r = tid >> 2, c = tid & 3;
    int node = nbase + r;
    union { bf16 hh[32]; uint4 u[4]; } t;
    if (node < n) {
      int idx = (c < 2) ? deg[node] : lab[node];
      const float* srcp = (c < 2) ? (ed + (size_t)idx * 64 + c * 32)
                                  : (el + (size_t)idx * 64 + (c - 2) * 32);
#pragma unroll
      for (int j = 0; j < 8; ++j) {
        float4 f = ((const float4*)srcp)[j];
        t.hh[j * 4 + 0] = (bf16)f.x; t.hh[j * 4 + 1] = (bf16)f.y;
        t.hh[j * 4 + 2] = (bf16)f.z; t.hh[j * 4 + 3] = (bf16)f.w;
      }
    } else {
#pragma unroll
      for (int j = 0; j < 4; ++j) t.u[j] = uint4{0, 0, 0, 0};
    }
#pragma unroll
    for (int j = 0; j < 4; ++j) *(uint4*)&As[r][c * 32 + j * 8] = t.u[j];
    const float4* wp = (const float4*)(W + r * 128 + c * 32);
#pragma unroll
    for (int j = 0; j < 4; ++j) {
      float4 f0 = wp[j * 2], f1 = wp[j * 2 + 1];
      union { bf16 h[8]; uint4 u; } tw;
      tw.h[0] = (bf16)f0.x; tw.h[1] = (bf16)f0.y; tw.h[2] = (bf16)f0.z; tw.h[3] = (bf16)f0.w;
      tw.h[4] = (bf16)f1.x; tw.h[5] = (bf16)f1.y; tw.h[6] = (bf16)f1.z; tw.h[7] = (bf16)f1.w;
      *(uint4*)&Bs[r][c * 32 + j * 8] = tw.u;
    }
  }
  __syncthreads();
  int l = tid & 63, w = tid >> 6, m = l & 15, quad = l >> 4;
  f32x4 acc[4] = {{0.f, 0.f, 0.f, 0.f}, {0.f, 0.f, 0.f, 0.f},
                  {0.f, 0.f, 0.f, 0.f}, {0.f, 0.f, 0.f, 0.f}};
#pragma unroll
  for (int k0 = 0; k0 < 128; k0 += 32) {
    bf16x8 a = *(const bf16x8*)&As[w * 16 + m][k0 + quad * 8];
#pragma unroll
    for (int t = 0; t < 4; ++t) {
      bf16x8 b = *(const bf16x8*)&Bs[t * 16 + m][k0 + quad * 8];
      acc[t] = __builtin_amdgcn_mfma_f32_16x16x32_bf16(a, b, acc[t], 0, 0, 0);
    }
  }
#pragma unroll
  for (int t = 0; t < 4; ++t)
#pragma unroll
    for (int r4 = 0; r4 < 4; ++r4) {
      int node = nbase + w * 16 + quad * 4 + r4;
      if (node < n) y[(size_t)node * 64 + t * 16 + m] = (bf16)acc[t][r4];
    }
}

// ------- MFMA GEMM (layers 1,2) -------
__global__ __launch_bounds__(256) void mfma_gemm_bn(
    const bf16* __restrict__ hin, const float* __restrict__ st,
    const float* __restrict__ g, const float* __restrict__ be, float inv_n,
    const float* __restrict__ W, bf16* __restrict__ z,
    bf16* __restrict__ y, int n) {
  __shared__ bf16 As[64][72];
  __shared__ bf16 Bs[64][72];
  __shared__ float ssc[64], ssh[64];
  int tid = threadIdx.x;
  int nbase = blockIdx.x * 64;
  if (tid < 64) {
    float sc, sh;
    bn_coeffs(st, g, be, inv_n, tid, sc, sh);
    ssc[tid] = sc; ssh[tid] = sh;
  }
  __syncthreads();
  {
    int r = tid >> 2, c = tid & 3;
    int node = nbase + r;
    union { bf16 h[16]; uint4 u[2]; } t;
    if (node < n) {
      const uint4* p = (const uint4*)(hin + (size_t)node * 64 + c * 16);
      union { uint4 u; bf16 h[8]; } a0, a1;
      a0.u = p[0]; a1.u = p[1];
#pragma unroll
      for (int j = 0; j < 8; ++j) {
        int d = c * 16 + j;
        float v = (float)a0.h[j] * ssc[d] + ssh[d];
        v = (v >= 0.f) ? v : 0.01f * v;
        t.h[j] = (bf16)v;
      }
#pragma unroll
      for (int j = 0; j < 8; ++j) {
        int d = c * 16 + 8 + j;
        float v = (float)a1.h[j] * ssc[d] + ssh[d];
        v = (v >= 0.f) ? v : 0.01f * v;
        t.h[8 + j] = (bf16)v;
      }
      *(uint4*)(z + (size_t)node * 64 + c * 16) = t.u[0];
      *(uint4*)(z + (size_t)node * 64 + c * 16 + 8) = t.u[1];
    } else {
      t.u[0] = uint4{0, 0, 0, 0}; t.u[1] = uint4{0, 0, 0, 0};
    }
    *(uint4*)&As[r][c * 16] = t.u[0];
    *(uint4*)&As[r][c * 16 + 8] = t.u[1];
    const float4* wp = (const float4*)(W + r * 64 + c * 16);
#pragma unroll
    for (int j = 0; j < 2; ++j) {
      float4 f0 = wp[j * 2], f1 = wp[j * 2 + 1];
      union { bf16 h[8]; uint4 u; } tw;
      tw.h[0] = (bf16)f0.x; tw.h[1] = (bf16)f0.y; tw.h[2] = (bf16)f0.z; tw.h[3] = (bf16)f0.w;
      tw.h[4] = (bf16)f1.x; tw.h[5] = (bf16)f1.y; tw.h[6] = (bf16)f1.z; tw.h[7] = (bf16)f1.w;
      *(uint4*)&Bs[r][c * 16 + j * 8] = tw.u;
    }
  }
  __syncthreads();
  int l = tid & 63, w = tid >> 6, m = l & 15, quad = l >> 4;
  f32x4 acc[4] = {{0.f, 0.f, 0.f, 0.f}, {0.f, 0.f, 0.f, 0.f},
                  {0.f, 0.f, 0.f, 0.f}, {0.f, 0.f, 0.f, 0.f}};
#pragma unroll
  for (int k0 = 0; k0 < 64; k0 += 32) {
    bf16x8 a = *(const bf16x8*)&As[w * 16 + m][k0 + quad * 8];
#pragma unroll
    for (int t = 0; t < 4; ++t) {
      bf16x8 b = *(const bf16x8*)&Bs[t * 16 + m][k0 + quad * 8];
      acc[t] = __builtin_amdgcn_mfma_f32_16x16x32_bf16(a, b, acc[t], 0, 0, 0);
    }
  }
#pragma unroll
  for (int t = 0; t < 4; ++t)
#pragma unroll
    for (int r4 = 0; r4 < 4; ++r4) {
      int node = nbase + w * 16 + quad * 4 + r4;
      if (node < n) y[(size_t)node * 64 + t * 16 + m] = (bf16)acc[t][r4];
    }
}

// ------- gather v4 (session-best measured: 77.7us/dispatch, total 521.7us) -------
// lane = [g:3][lh:3]; group g owns node nb+g; lane lh holds dims [8*lh, 8*lh+8)
// as one uint4; 8 lanes cover the 128B row -> one vmem instruction touches 8
// DIFFERENT lines; 8-deep unroll = nominal 64 lines in flight per wave. The
// launch_bounds(256,6) cap (VGPR=40) makes the compiler spill in-flight
// payloads to scratch (~98MB round-trip), yet this measured FASTER than the
// spill-free uint2 variant (80.5us): scratch streams at high BW underneath the
// random y-load critical path, while the 8-lines-per-instruction format issues
// more random lines per cycle. Session conclusion: gather is line-rate bound
// at ~20G random lines/s (MLP scaling, XCD-L2 tiling, occupancy, registers,
// and colidx-chain-split all exhausted: v1-v8). This is the structural floor.
__global__ __launch_bounds__(256, 6) void gather_kernel(
    const bf16* __restrict__ y, const int* __restrict__ rowptr,
    const int* __restrict__ colidx, const float* __restrict__ bias,
    bf16* __restrict__ h, float* __restrict__ stats, int n) {
  __shared__ float s_sum[64], s_sq[64];
  int tid = threadIdx.x;
  if (tid < 64) { s_sum[tid] = 0.f; s_sq[tid] = 0.f; }
  __syncthreads();
  int lane = tid & 63, wv = tid >> 6;
  int g = lane >> 3, lh = lane & 7;
  const uint4* y4 = (const uint4*)y;
  uint4* h4 = (uint4*)h;
  float bj[8];
#pragma unroll
  for (int j = 0; j < 8; ++j) bj[j] = bias[8 * lh + j];
  float p[8] = {0.f, 0.f, 0.f, 0.f, 0.f, 0.f, 0.f, 0.f};
  float q[8] = {0.f, 0.f, 0.f, 0.f, 0.f, 0.f, 0.f, 0.f};
  int stride = gridDim.x * 32;

#define ACC8(d)                                                      \
  {                                                                  \
    union { unsigned u; float f; } t_;                               \
    t_.u = (d).x << 16;         acc[0] += t_.f;                      \
    t_.u = (d).x & 0xFFFF0000u; acc[1] += t_.f;                      \
    t_.u = (d).y << 16;         acc[2] += t_.f;                      \
    t_.u = (d).y & 0xFFFF0000u; acc[3] += t_.f;                      \
    t_.u = (d).z << 16;         acc[4] += t_.f;                      \
    t_.u = (d).z & 0xFFFF0000u; acc[5] += t_.f;                      \
    t_.u = (d).w << 16;         acc[6] += t_.f;                      \
    t_.u = (d).w & 0xFFFF0000u; acc[7] += t_.f;                      \
  }

  for (int nb = (blockIdx.x * 4 + wv) * 8; nb < n; nb += stride) {
    int node = nb + g;
    bool valid = node < n;
    int e = valid ? rowptr[node] : 0;
    int f = valid ? rowptr[node + 1] : 0;
    float acc[8] = {0.f, 0.f, 0.f, 0.f, 0.f, 0.f, 0.f, 0.f};
    // main: 8 edges per group per trip; runs while ANY group has >=8 left
    for (;;) {
      bool a = (e + 8 <= f);
      if (__ballot(a) == 0ull) break;
      if (a) {
        int s0 = colidx[e + 0], s1 = colidx[e + 1], s2 = colidx[e + 2], s3 = colidx[e + 3];
        int s4 = colidx[e + 4], s5 = colidx[e + 5], s6 = colidx[e + 6], s7 = colidx[e + 7];
        uint4 d0 = y4[(size_t)s0 * 8 + lh];
        uint4 d1 = y4[(size_t)s1 * 8 + lh];
        uint4 d2 = y4[(size_t)s2 * 8 + lh];
        uint4 d3 = y4[(size_t)s3 * 8 + lh];
        uint4 d4 = y4[(size_t)s4 * 8 + lh];
        uint4 d5 = y4[(size_t)s5 * 8 + lh];
        uint4 d6 = y4[(size_t)s6 * 8 + lh];
        uint4 d7 = y4[(size_t)s7 * 8 + lh];
        ACC8(d0); ACC8(d1); ACC8(d2); ACC8(d3);
        ACC8(d4); ACC8(d5); ACC8(d6); ACC8(d7);
        e += 8;
      }
    }
    // mid: one 4-edge trip (remainder is <=7 after main)
    {
      bool a = (e + 4 <= f);
      if (__ballot(a) != 0ull) {
        if (a) {
          int s0 = colidx[e + 0], s1 = colidx[e + 1], s2 = colidx[e + 2], s3 = colidx[e + 3];
          uint4 d0 = y4[(size_t)s0 * 8 + lh];
          uint4 d1 = y4[(size_t)s1 * 8 + lh];
          uint4 d2 = y4[(size_t)s2 * 8 + lh];
          uint4 d3 = y4[(size_t)s3 * 8 + lh];
          ACC8(d0); ACC8(d1); ACC8(d2); ACC8(d3);
          e += 4;
        }
      }
    }
    // tail: up to 3 predicated single-edge steps (straight-line, if-converted)
#pragma unroll
    for (int t = 0; t < 3; ++t) {
      bool a = e < f;
      if (a) {
        int s = colidx[e];
        uint4 d = y4[(size_t)s * 8 + lh];
        ACC8(d);
        ++e;
      }
    }
    if (valid) {
      uint4 sd = y4[(size_t)node * 8 + lh];
      float sv[8];
      {
        union { unsigned u; float f; } t_;
        t_.u = sd.x << 16;         sv[0] = t_.f;
        t_.u = sd.x & 0xFFFF0000u; sv[1] = t_.f;
        t_.u = sd.y << 16;         sv[2] = t_.f;
        t_.u = sd.y & 0xFFFF0000u; sv[3] = t_.f;
        t_.u = sd.z << 16;         sv[4] = t_.f;
        t_.u = sd.z & 0xFFFF0000u; sv[5] = t_.f;
        t_.u = sd.w << 16;         sv[6] = t_.f;
        t_.u = sd.w & 0xFFFF0000u; sv[7] = t_.f;
      }
      union { bf16 hh[8]; uint4 u; } o;
#pragma unroll
      for (int j = 0; j < 8; ++j) {
        float v = acc[j] + sv[j] + bj[j];
        o.hh[j] = (bf16)v;
        p[j] += v;
        q[j] += v * v;
      }
      h4[(size_t)node * 8 + lh] = o.u;
    }
  }
#undef ACC8
#pragma unroll
  for (int j = 0; j < 8; ++j) {
    atomicAdd(&s_sum[8 * lh + j], p[j]);
    atomicAdd(&s_sq[8 * lh + j], q[j]);
  }
  __syncthreads();
  if (tid < 64) {
    atomicAdd(&stats[tid], s_sum[tid]);
    atomicAdd(&stats[64 + tid], s_sq[tid]);
  }
}

// ------- final MLP over concat [emb(deg,lab)|z1|z2|bnleaky(h2)] (320 -> 64), MFMA -------
__global__ __launch_bounds__(256) void mfma_final(
    const int* __restrict__ deg, const int* __restrict__ lab,
    const float* __restrict__ ed, const float* __restrict__ el,
    const bf16* __restrict__ z1, const bf16* __restrict__ z2,
    const bf16* __restrict__ h2, const float* __restrict__ st2,
    const float* __restrict__ g2, const float* __restrict__ be2, float inv_n,
    const float* __restrict__ fw1, const float* __restrict__ fb1,
    bf16* __restrict__ hf, float* __restrict__ stats, int n) {
  __shared__ bf16 As[64][136];
  __shared__ bf16 Bs[64][136];
  __shared__ float s_sum[64], s_sq[64], ssc[64], ssh[64];
  int tid = threadIdx.x;
  if (tid < 64) {
    s_sum[tid] = 0.f; s_sq[tid] = 0.f;
    float sc, sh;
    bn_coeffs(st2, g2, be2, inv_n, tid, sc, sh);
    ssc[tid] = sc; ssh[tid] = sh;
  }
  int nbase = blockIdx.x * 64;
  int l = tid & 63, w = tid >> 6, m = l & 15, quad = l >> 4;
  int r = tid >> 2, c = tid & 3;
  int node_r = nbase + r;
  f32x4 acc[4] = {{0.f, 0.f, 0.f, 0.f}, {0.f, 0.f, 0.f, 0.f},
                  {0.f, 0.f, 0.f, 0.f}, {0.f, 0.f, 0.f, 0.f}};

#pragma unroll
  for (int seg = 0; seg < 4; ++seg) {
    __syncthreads();
    if (seg == 0) {
      union { bf16 hh[32]; uint4 u[4]; } t;
      if (node_r < n) {
        int idx = (c < 2) ? deg[node_r] : lab[node_r];
        const float* srcp = (c < 2) ? (ed + (size_t)idx * 64 + c * 32)
                                    : (el + (size_t)idx * 64 + (c - 2) * 32);
#pragma unroll
        for (int j = 0; j < 8; ++j) {
          float4 f = ((const float4*)srcp)[j];
          t.hh[j * 4 + 0] = (bf16)f.x; t.hh[j * 4 + 1] = (bf16)f.y;
          t.hh[j * 4 + 2] = (bf16)f.z; t.hh[j * 4 + 3] = (bf16)f.w;
        }
      } else {
#pragma unroll
        for (int j = 0; j < 4; ++j) t.u[j] = uint4{0, 0, 0, 0};
      }
#pragma unroll
      for (int j = 0; j < 4; ++j) *(uint4*)&As[r][c * 32 + j * 8] = t.u[j];
      const float4* wp = (const float4*)(fw1 + r * 320 + c * 32);
#pragma unroll
      for (int j = 0; j < 4; ++j) {
        float4 f0 = wp[j * 2], f1 = wp[j * 2 + 1];
        union { bf16 h[8]; uint4 u; } tw;
        tw.h[0] = (bf16)f0.x; tw.h[1] = (bf16)f0.y; tw.h[2] = (bf16)f0.z; tw.h[3] = (bf16)f0.w;
        tw.h[4] = (bf16)f1.x; tw.h[5] = (bf16)f1.y; tw.h[6] = (bf16)f1.z; tw.h[7] = (bf16)f1.w;
        *(uint4*)&Bs[r][c * 32 + j * 8] = tw.u;
      }
    } else if (seg < 3) {
      const bf16* zz = (seg == 1) ? z1 : z2;
      uint4 v[2] = {};
      if (node_r < n) {
        const uint4* p = (const uint4*)(zz + (size_t)node_r * 64 + c * 16);
        v[0] = p[0]; v[1] = p[1];
      }
      *(uint4*)&As[r][c * 16] = v[0];
      *(uint4*)&As[r][c * 16 + 8] = v[1];
      const float4* wp = (const float4*)(fw1 + r * 320 + (seg == 1 ? 128 : 192) + c * 16);
#pragma unroll
      for (int j = 0; j < 2; ++j) {
        float4 f0 = wp[j * 2], f1 = wp[j * 2 + 1];
        union { bf16 h[8]; uint4 u; } t;
        t.h[0] = (bf16)f0.x; t.h[1] = (bf16)f0.y; t.h[2] = (bf16)f0.z; t.h[3] = (bf16)f0.w;
        t.h[4] = (bf16)f1.x; t.h[5] = (bf16)f1.y; t.h[6] = (bf16)f1.z; t.h[7] = (bf16)f1.w;
        *(uint4*)&Bs[r][c * 16 + j * 8] = t.u;
      }
    } else {
      union { bf16 h[16]; uint4 u[2]; } t;
      if (node_r < n) {
        const uint4* p = (const uint4*)(h2 + (size_t)node_r * 64 + c * 16);
        union { uint4 u; bf16 h[8]; } a0, a1;
        a0.u = p[0]; a1.u = p[1];
#pragma unroll
        for (int j = 0; j < 8; ++j) {
          int d = c * 16 + j;
          float v = (float)a0.h[j] * ssc[d] + ssh[d];
          v = (v >= 0.f) ? v : 0.01f * v;
          t.h[j] = (bf16)v;
        }
#pragma unroll
        for (int j = 0; j < 8; ++j) {
          int d = c * 16 + 8 + j;
          float v = (float)a1.h[j] * ssc[d] + ssh[d];
          v = (v >= 0.f) ? v : 0.01f * v;
          t.h[8 + j] = (bf16)v;
        }
      } else {
        t.u[0] = uint4{0, 0, 0, 0}; t.u[1] = uint4{0, 0, 0, 0};
      }
      *(uint4*)&As[r][c * 16] = t.u[0];
      *(uint4*)&As[r][c * 16 + 8] = t.u[1];
      const float4* wp = (const float4*)(fw1 + r * 320 + 256 + c * 16);
#pragma unroll
      for (int j = 0; j < 2; ++j) {
        float4 f0 = wp[j * 2], f1 = wp[j * 2 + 1];
        union { bf16 h[8]; uint4 u; } tw;
        tw.h[0] = (bf16)f0.x; tw.h[1] = (bf16)f0.y; tw.h[2] = (bf16)f0.z; tw.h[3] = (bf16)f0.w;
        tw.h[4] = (bf16)f1.x; tw.h[5] = (bf16)f1.y; tw.h[6] = (bf16)f1.z; tw.h[7] = (bf16)f1.w;
        *(uint4*)&Bs[r][c * 16 + j * 8] = tw.u;
      }
    }
    __syncthreads();
    int kmax = (seg == 0) ? 128 : 64;
    for (int k0 = 0; k0 < kmax; k0 += 32) {
      bf16x8 a = *(const bf16x8*)&As[w * 16 + m][k0 + quad * 8];
#pragma unroll
      for (int t = 0; t < 4; ++t) {
        bf16x8 b = *(const bf16x8*)&Bs[t * 16 + m][k0 + quad * 8];
        acc[t] = __builtin_amdgcn_mfma_f32_16x16x32_bf16(a, b, acc[t], 0, 0, 0);
      }
    }
  }

#pragma unroll
  for (int t = 0; t < 4; ++t) {
    int o = t * 16 + m;
    float bv = fb1[o];
    float s = 0.f, q = 0.f;
#pragma unroll
    for (int r4 = 0; r4 < 4; ++r4) {
      int node = nbase + w * 16 + quad * 4 + r4;
      if (node < n) {
        float v = acc[t][r4] + bv;
        hf[(size_t)node * 64 + o] = (bf16)v;
        s += v;
        q += v * v;
      }
    }
    atomicAdd(&s_sum[o], s);
    atomicAdd(&s_sq[o], q);
  }
  __syncthreads();
  if (tid < 64) {
    atomicAdd(&stats[tid], s_sum[tid]);
    atomicAdd(&stats[64 + tid], s_sq[tid]);
  }
}

// ---------------- head ----------------
__global__ __launch_bounds__(256) void final_out_kernel(
    const bf16* __restrict__ hf, const float* __restrict__ st,
    const float* __restrict__ g, const float* __restrict__ be, float inv_n,
    const float* __restrict__ fw2, const float* __restrict__ fb2,
    float* __restrict__ out, int n) {
  int lane = threadIdx.x & 63;
  int node = blockIdx.x * 4 + (threadIdx.x >> 6);
  if (node >= n) return;
  float sc, sh;
  bn_coeffs(st, g, be, inv_n, lane, sc, sh);
  float v = (float)hf[(size_t)node * 64 + lane] * sc + sh;
  v = (v >= 0.f) ? v : 0.01f * v;
  v *= fw2[lane];
#pragma unroll
  for (int off = 32; off > 0; off >>= 1) v += __shfl_xor(v, off);
  if (lane == 0) out[node] = 1.f / (1.f + expf(-(v + fb2[0])));
}

extern "C" void kernel_launch(void* const* d_in, const int* in_sizes, int n_in,
                              void* d_out, int out_size, void* d_ws, size_t ws_size,
                              hipStream_t stream) {
  const int* node_deg = (const int*)d_in[0];
  const int* node_lab = (const int*)d_in[1];
  const int* ei = (const int*)d_in[2];
  const float* emb_deg = (const float*)d_in[3];
  const float* emb_lab = (const float*)d_in[4];
  const float* w0 = (const float*)d_in[5];
  const float* b0 = (const float*)d_in[6];
  const float* g0 = (const float*)d_in[7];
  const float* be0 = (const float*)d_in[8];
  const float* w1 = (const float*)d_in[9];
  const float* b1 = (const float*)d_in[10];
  const float* g1 = (const float*)d_in[11];
  const float* be1 = (const float*)d_in[12];
  const float* w2 = (const float*)d_in[13];
  const float* b2 = (const float*)d_in[14];
  const float* g2 = (const float*)d_in[15];
  const float* be2 = (const float*)d_in[16];
  const float* fw1 = (const float*)d_in[17];
  const float* fb1 = (const float*)d_in[18];
  const float* fg = (const float*)d_in[19];
  const float* fbe = (const float*)d_in[20];
  const float* fw2 = (const float*)d_in[21];
  const float* fb2 = (const float*)d_in[22];

  const int N = in_sizes[0];
  const int E = in_sizes[2] / 2;
  const int* src = ei;
  const int* dst = ei + E;
  const int NB = (N + 63) >> 6;
  const int CH = (E + NBLK - 1) / NBLK;
  const float inv_n = 1.0f / N;

  char* ws = (char*)d_ws;
  size_t off = 0;
  auto alloc = [&](size_t bytes) {
    void* p = ws + off;
    off += (bytes + 255) & ~(size_t)255;
    return p;
  };
  bf16* z1 = (bf16*)alloc((size_t)N * 64 * 2);
  bf16* z2 = (bf16*)alloc((size_t)N * 64 * 2);
  bf16* h = (bf16*)alloc((size_t)N * 64 * 2);
  bf16* y = (bf16*)alloc((size_t)N * 64 * 2);  // reused as hf at the end
  int* packed = (int*)alloc((size_t)E * 4);
  int* colidx = (int*)alloc((size_t)E * 4);
  int* rowptr = (int*)alloc((size_t)(N + 1) * 4);
  int* cnt = (int*)alloc((size_t)NBLK * NB * 4);
  int* woff = (int*)alloc((size_t)NBLK * NB * 4);
  int* btot = (int*)alloc((size_t)NB * 4);
  int* bucketptr = (int*)alloc((size_t)(NB + 1) * 4);
  float* stats = (float*)alloc(4 * 256 * 4);

  hipMemsetAsync(stats, 0, 4 * 256 * 4, stream);

  // CSR build
  bin_hist_kernel<<<NBLK, 256, 0, stream>>>(dst, cnt, E, CH, NB);
  bin_tot_kernel<<<(NB + 255) / 256, 256, 0, stream>>>(cnt, btot, NB);
  scan_buckets_kernel<<<1, 256, 0, stream>>>(btot, bucketptr, NB);
  bin_off_kernel<<<(NB + 255) / 256, 256, 0, stream>>>(cnt, bucketptr, woff, NB);
  bin_scatter_kernel<<<NBLK, 256, 0, stream>>>(src, dst, woff, packed, E, CH, NB);
  csr_finalize_kernel<<<NB, 256, 0, stream>>>(packed, bucketptr, rowptr, colidx, N, E);

  int ngrid = (N + 63) / 64;
  // gather: 8 nodes/wave x 4 waves = 32 nodes/block/sweep; grid sized for ~4
  // balanced sweeps (782 blocks @ N=100k) — the session-best measured config.
  int ggrid = (N + 127) / 128;
  if (ggrid > 2048) ggrid = 2048;
  if (ggrid < 1) ggrid = 1;

  // layer 0 (embedding fused into GEMM; x0 never materialized)
  mfma_gemm0<<<ngrid, 256, 0, stream>>>(node_deg, node_lab, emb_deg, emb_lab, w0, y, N);
  gather_kernel<<<ggrid, 256, 0, stream>>>(y, rowptr, colidx, b0, h, stats, N);
  // layer 1
  mfma_gemm_bn<<<ngrid, 256, 0, stream>>>(h, stats, g0, be0, inv_n, w1, z1, y, N);
  gather_kernel<<<ggrid, 256, 0, stream>>>(y, rowptr, colidx, b1, h, stats + 256, N);
  // layer 2
  mfma_gemm_bn<<<ngrid, 256, 0, stream>>>(h, stats + 256, g1, be1, inv_n, w2, z2, y, N);
  gather_kernel<<<ggrid, 256, 0, stream>>>(y, rowptr, colidx, b2, h, stats + 512, N);
  // final MLP 320 -> 64 (embedding re-gathered inline)
  mfma_final<<<ngrid, 256, 0, stream>>>(node_deg, node_lab, emb_deg, emb_lab, z1, z2, h,
                                        stats + 512, g2, be2, inv_n, fw1, fb1, y,
                                        stats + 768, N);
  final_out_kernel<<<(N + 3) / 4, 256, 0, stream>>>(y, stats + 768, fg, fbe, inv_n,
                                                    fw2, fb2, (float*)d_out, N);
}